// Round 7
// baseline (266.104 us; speedup 1.0000x reference)
//
#include <hip/hip_runtime.h>
#include <math.h>

#define HID 128
typedef unsigned int uint;
typedef unsigned short u16;
typedef __attribute__((ext_vector_type(8))) __bf16 bf16x8;
typedef __attribute__((ext_vector_type(4))) float f32x4;
typedef __attribute__((ext_vector_type(2))) float f32x2;

// ---------------- bf16 helpers (RNE) ----------------

__device__ __forceinline__ uint pack_bf2(float x, float y) {
    union { float f; uint u; } a, b;
    a.f = x; b.f = y;
    uint lo = (a.u + 0x7fffu + ((a.u >> 16) & 1u)) >> 16;
    uint hi = (b.u + 0x7fffu + ((b.u >> 16) & 1u)) & 0xffff0000u;
    return lo | hi;
}

__device__ __forceinline__ unsigned short bf16r(float x) {
    union { float f; uint u; } a; a.f = x;
    return (unsigned short)((a.u + 0x7fffu + ((a.u >> 16) & 1u)) >> 16);
}

__device__ __forceinline__ f32x2 bf2f(uint v) {
    union { uint u[2]; f32x2 f; } r;
    r.u[0] = v << 16;
    r.u[1] = v & 0xffff0000u;
    return r.f;
}

__device__ __forceinline__ f32x2 mk2(float s) { f32x2 r; r.x = s; r.y = s; return r; }
__device__ __forceinline__ f32x2 max2z(f32x2 a) {
    f32x2 r; r.x = fmaxf(a.x, 0.f); r.y = fmaxf(a.y, 0.f); return r;
}

// DPP-based add of a lane-permuted copy: single VALU op chain, no LDS pipe.
template<int CTRL>
__device__ __forceinline__ float dpp_add(float x) {
    union { float f; int i; } u, r;
    u.f = x;
    r.i = __builtin_amdgcn_update_dpp(0, u.i, CTRL, 0xf, 0xf, true);
    return x + r.f;
}

// ---------------- fused prep + hist_rank ----------------
// blocks < EB: histogram + within-bucket rank (atomic return value)
// blocks >= EB: composite weights Wc = W2 @ [Wm1_top|Wm1_mid] (bf16 MFMA frag
// order) and brow = b2 @ [...] + [bm1|0].
__global__ void prep_hist(const int* __restrict__ dst, int* __restrict__ cnt,
                          int* __restrict__ rank, int E, int EB,
                          const float* __restrict__ W2, const float* __restrict__ Wm1,
                          const float* __restrict__ b2, const float* __restrict__ bm1,
                          uint* __restrict__ fWc, float* __restrict__ brow) {
    if ((int)blockIdx.x < EB) {
        int e = blockIdx.x * blockDim.x + threadIdx.x;
        if (e < E) rank[e] = atomicAdd(&cnt[dst[e]], 1);
        return;
    }
    int t0 = ((int)blockIdx.x - EB) * blockDim.x + threadIdx.x;
    if (t0 < 65536) {       // 16384 outputs * 4 K-slices
        int ks = t0 & 3;
        int i = t0 >> 2;
        int p = i & 3, lane = (i >> 2) & 63, kk = (i >> 8) & 3, ct = i >> 10;
        int k = kk * 32 + (lane >> 4) * 8 + p * 2;
        int n2 = ct * 16 + (lane & 15);
        const float* wmc = (n2 < 128) ? (Wm1 + n2) : (Wm1 + 128 * HID + (n2 - 128));
        const float* w2r0 = W2 + (size_t)k * HID + ks * 32;
        const float* w2r1 = w2r0 + HID;
        const float* wm = wmc + (size_t)(ks * 32) * HID;
        float d0 = 0.f, d1 = 0.f;
        #pragma unroll 8
        for (int j = 0; j < 32; ++j) {
            float w = wm[(size_t)j * HID];
            d0 += w2r0[j] * w;
            d1 += w2r1[j] * w;
        }
        d0 = dpp_add<0xB1>(d0); d0 = dpp_add<0x4E>(d0);
        d1 = dpp_add<0xB1>(d1); d1 = dpp_add<0x4E>(d1);
        if (ks == 0) fWc[i] = pack_bf2(d0, d1);
    } else if (t0 < 65536 + 1024) {
        int r = t0 - 65536;
        int ks = r & 3;
        int i = r >> 2;
        const float* wmc = (i < 128) ? (Wm1 + i) : (Wm1 + 128 * HID + (i - 128));
        float d = 0.f;
        for (int j = ks * 32; j < ks * 32 + 32; ++j) d += b2[j] * wmc[(size_t)j * HID];
        d = dpp_add<0xB1>(d); d = dpp_add<0x4E>(d);
        if (ks == 0) brow[i] = d + ((i < 128) ? bm1[i] : 0.f);
    }
}

// ---------------- scan1x: block-local exclusive scan + dis + xps ----------------
__global__ void scan1x(const int* __restrict__ cnt, int* __restrict__ excl,
                       int* __restrict__ bsum, float* __restrict__ dis,
                       const float* __restrict__ x, uint4* __restrict__ xps, int N) {
    __shared__ int sh[256];
    int tid = threadIdx.x;
    int gid = blockIdx.x * 256 + tid;
    int v = (gid < N) ? cnt[gid] : 0;
    sh[tid] = v;
    __syncthreads();
    for (int o = 1; o < 256; o <<= 1) {
        int t = (tid >= o) ? sh[tid - o] : 0;
        __syncthreads();
        sh[tid] += t;
        __syncthreads();
    }
    if (gid < N) {
        excl[gid] = sh[tid] - v;
        float dn = rsqrtf((float)v + 1.0f);   // deg incl. self-loop
        dis[gid] = dn;
        const float* xr = x + (size_t)gid * 5;
        uint4 pk;
        pk.x = pack_bf2(dn * xr[0], dn * xr[1]);
        pk.y = pack_bf2(dn * xr[2], dn * xr[3]);
        pk.z = pack_bf2(dn * xr[4], 0.f);
        pk.w = 0u;
        xps[gid] = pk;
    }
    if (tid == 255) bsum[blockIdx.x] = sh[255];
}

// ---------------- fused scatter + rowptr finalize (NO atomics) ----------------
// All blocks redundantly scan bsum (<=256 entries) in LDS.
// blocks < EB:  pos = excl[d] + ex[d>>8] + rank[e]; csr2[pos], ear[pos] stores.
//               ear stores are nontemporal (consumed 3 dispatches later; keep
//               L2 for xps/csr2 which layer1 needs hot).
// blocks >= EB: rowptr[gid] = excl[gid] + ex[gid>>8]; rowptr[N] = E.
__global__ void scatter_fin(const int* __restrict__ src, const int* __restrict__ dst,
                            const int* __restrict__ excl, const int* __restrict__ bsum,
                            const int* __restrict__ rank,
                            const float* __restrict__ ea,
                            uint2* __restrict__ csr2, float* __restrict__ ear,
                            int* __restrict__ rowptr,
                            int use_ear, int E, int N, int NB, int EB) {
    __shared__ int sh[256];
    __shared__ int ex[256];
    int tid = threadIdx.x;
    int v = (tid < NB) ? bsum[tid] : 0;
    sh[tid] = v;
    __syncthreads();
    for (int o = 1; o < 256; o <<= 1) {
        int t = (tid >= o) ? sh[tid - o] : 0;
        __syncthreads();
        sh[tid] += t;
        __syncthreads();
    }
    ex[tid] = sh[tid] - v;
    __syncthreads();

    if ((int)blockIdx.x < EB) {
        int e = blockIdx.x * 256 + tid;
        if (e < E) {
            int d = dst[e];
            int pos = excl[d] + ex[d >> 8] + rank[e];
            csr2[pos] = make_uint2((uint)src[e] | ((uint)d << 16), (uint)e);
            if (use_ear) {
                f32x4 ev = *(const f32x4*)(ea + (size_t)e * 4);
                __builtin_nontemporal_store(ev, (f32x4*)(ear + (size_t)pos * 4));
            }
        }
    } else {
        int gid = ((int)blockIdx.x - EB) * 256 + tid;
        if (gid < N) rowptr[gid] = excl[gid] + ex[gid >> 8];
        if (gid == N) rowptr[N] = E;
    }
}

// ---------------- fused layer-1: hs1 = dis * relu( (S·x) @ W1 + b1 ) ----------------
// 4 lanes per node (quad): edge gathers split 4-way + DPP quad-reduce.
// xps is 800 KB total -> L2-resident, so the random gathers are cheap.
// Also zero-fills the sentinel row hs1[N] (used by agg_gemm's clamped slots).
__launch_bounds__(256)
__global__ void layer1_kernel(const uint4* __restrict__ xps, const uint2* __restrict__ csr2,
                              const int* __restrict__ rowptr, const float* __restrict__ dis,
                              const float* __restrict__ W1, const float* __restrict__ b1,
                              uint* __restrict__ hs1, int N) {
    __shared__ float sW[5 * HID];
    __shared__ float sb[HID];
    int tid = threadIdx.x;
    for (int i = tid; i < 5 * HID; i += 256) sW[i] = W1[i];
    for (int i = tid; i < HID; i += 256) sb[i] = b1[i];
    if (blockIdx.x == 0 && tid < 16) {
        uint4 z; z.x = 0u; z.y = 0u; z.z = 0u; z.w = 0u;
        ((uint4*)hs1)[(size_t)N * 16 + tid] = z;    // sentinel zero row
    }
    __syncthreads();

    int sub = tid & 3;
    int n = blockIdx.x * 64 + (tid >> 2);
    if (n >= N) return;
    int beg = rowptr[n], end = rowptr[n + 1];
    float a0 = 0.f, a1 = 0.f, a2 = 0.f, a3 = 0.f, a4 = 0.f;
    for (int i = beg + sub; i < end; i += 4) {
        uint s = csr2[i].x & 0xffffu;
        uint4 v = xps[s];
        f32x2 v01 = bf2f(v.x), v23 = bf2f(v.y), v4 = bf2f(v.z);
        a0 += v01.x; a1 += v01.y; a2 += v23.x; a3 += v23.y; a4 += v4.x;
    }
    a0 = dpp_add<0xB1>(a0); a0 = dpp_add<0x4E>(a0);
    a1 = dpp_add<0xB1>(a1); a1 = dpp_add<0x4E>(a1);
    a2 = dpp_add<0xB1>(a2); a2 = dpp_add<0x4E>(a2);
    a3 = dpp_add<0xB1>(a3); a3 = dpp_add<0x4E>(a3);
    a4 = dpp_add<0xB1>(a4); a4 = dpp_add<0x4E>(a4);
    {
        uint4 v = xps[n];   // self-loop term
        f32x2 v01 = bf2f(v.x), v23 = bf2f(v.y), v4 = bf2f(v.z);
        a0 += v01.x; a1 += v01.y; a2 += v23.x; a3 += v23.y; a4 += v4.x;
    }
    float dn = dis[n];
    a0 *= dn; a1 *= dn; a2 *= dn; a3 *= dn; a4 *= dn;   // sx row

    uint* op = hs1 + (size_t)n * 64;
    #pragma unroll
    for (int p = 0; p < 16; ++p) {
        int q = p * 4 + sub;
        int j = q * 2;
        float t0 = sb[j]     + a0 * sW[j]     + a1 * sW[HID + j]     + a2 * sW[2*HID + j]
                             + a3 * sW[3*HID + j] + a4 * sW[4*HID + j];
        float t1 = sb[j + 1] + a0 * sW[j + 1] + a1 * sW[HID + j + 1] + a2 * sW[2*HID + j + 1]
                             + a3 * sW[3*HID + j + 1] + a4 * sW[4*HID + j + 1];
        op[q] = pack_bf2(fmaxf(t0, 0.f) * dn, fmaxf(t1, 0.f) * dn);
    }
}

// ---------------- fused aggregate + GEMM ----------------
// block = 4 waves = 16 nodes.  Phase 1: one 16-lane group per node; each lane owns
// 8 columns (its uint4 slice): no cross-lane ops, no barriers; 8-edge-deep gather
// loop with csr2-index prefetch; out-of-range slots hit the zero sentinel hs1[N].
// Phase 2: wave MFMAs the g tile against 4 of 16 column-tiles of Wc (+brow bias).
__launch_bounds__(256)
__global__ void agg_gemm(const uint4* __restrict__ hs1, const uint2* __restrict__ csr2,
                         const int* __restrict__ rowptr, const float* __restrict__ dis,
                         const uint4* __restrict__ Bf, const float* __restrict__ brow,
                         unsigned short* __restrict__ out, int N) {
    __shared__ uint gt[16][64];
    int tid = threadIdx.x;
    int wave = tid >> 6, lane = tid & 63;
    int gl = lane & 15, grp = lane >> 4;
    int nb = blockIdx.x * 16;
    int r = wave * 4 + grp;          // node slot 0..15 (group-per-node)
    int n = nb + r;
    const uint* cxp = (const uint*)csr2;   // stride-2 view of csr2[i].x

    f32x2 acc0 = mk2(0.f), acc1 = mk2(0.f), acc2 = mk2(0.f), acc3 = mk2(0.f);
    float dn = 0.f;
    if (n < N) {
        dn = dis[n];
        int beg = rowptr[n], end = rowptr[n + 1];
        int i = beg;
        if (i < end) {
            int lst = end - 1;
            uint cb[8];
            #pragma unroll
            for (int t = 0; t < 8; ++t) {
                int a = i + t; a = (a > lst) ? lst : a;
                cb[t] = cxp[(size_t)a * 2];
            }
            while (i < end) {
                uint ss[8];
                #pragma unroll
                for (int t = 0; t < 8; ++t)
                    ss[t] = (i + t < end) ? (cb[t] & 0xffffu) : (uint)N;
                #pragma unroll
                for (int t = 0; t < 8; ++t) {           // prefetch next oct
                    int a = i + 8 + t; a = (a > lst) ? lst : a;
                    cb[t] = cxp[(size_t)a * 2];
                }
                uint4 v0 = hs1[(size_t)ss[0] * 16 + gl];
                uint4 v1 = hs1[(size_t)ss[1] * 16 + gl];
                uint4 v2 = hs1[(size_t)ss[2] * 16 + gl];
                uint4 v3 = hs1[(size_t)ss[3] * 16 + gl];
                uint4 v4 = hs1[(size_t)ss[4] * 16 + gl];
                uint4 v5 = hs1[(size_t)ss[5] * 16 + gl];
                uint4 v6 = hs1[(size_t)ss[6] * 16 + gl];
                uint4 v7 = hs1[(size_t)ss[7] * 16 + gl];
                acc0 += bf2f(v0.x); acc1 += bf2f(v0.y); acc2 += bf2f(v0.z); acc3 += bf2f(v0.w);
                acc0 += bf2f(v1.x); acc1 += bf2f(v1.y); acc2 += bf2f(v1.z); acc3 += bf2f(v1.w);
                acc0 += bf2f(v2.x); acc1 += bf2f(v2.y); acc2 += bf2f(v2.z); acc3 += bf2f(v2.w);
                acc0 += bf2f(v3.x); acc1 += bf2f(v3.y); acc2 += bf2f(v3.z); acc3 += bf2f(v3.w);
                acc0 += bf2f(v4.x); acc1 += bf2f(v4.y); acc2 += bf2f(v4.z); acc3 += bf2f(v4.w);
                acc0 += bf2f(v5.x); acc1 += bf2f(v5.y); acc2 += bf2f(v5.z); acc3 += bf2f(v5.w);
                acc0 += bf2f(v6.x); acc1 += bf2f(v6.y); acc2 += bf2f(v6.z); acc3 += bf2f(v6.w);
                acc0 += bf2f(v7.x); acc1 += bf2f(v7.y); acc2 += bf2f(v7.z); acc3 += bf2f(v7.w);
                i += 8;
            }
        }
        {   // self-loop row
            uint4 sv = hs1[(size_t)n * 16 + gl];
            acc0 += bf2f(sv.x); acc1 += bf2f(sv.y); acc2 += bf2f(sv.z); acc3 += bf2f(sv.w);
        }
    }
    // write g tile row (dn = 0 zeros out-of-range nodes)
    gt[r][gl * 4 + 0] = pack_bf2(acc0.x * dn, acc0.y * dn);
    gt[r][gl * 4 + 1] = pack_bf2(acc1.x * dn, acc1.y * dn);
    gt[r][gl * 4 + 2] = pack_bf2(acc2.x * dn, acc2.y * dn);
    gt[r][gl * 4 + 3] = pack_bf2(acc3.x * dn, acc3.y * dn);
    __syncthreads();

    // phase 2: HsHd = g @ Wc + brow
    int quad = lane >> 4;
    bf16x8 afr[4];
    #pragma unroll
    for (int kk = 0; kk < 4; ++kk)
        afr[kk] = *(const bf16x8*)&gt[gl][kk * 16 + quad * 4];

    for (int cc = 0; cc < 4; ++cc) {
        int c = wave * 4 + cc;
        f32x4 acc = {0.f, 0.f, 0.f, 0.f};
        #pragma unroll
        for (int kk = 0; kk < 4; ++kk) {
            bf16x8 bfr = *(const bf16x8*)&Bf[(size_t)(c * 4 + kk) * 64 + lane];
            acc = __builtin_amdgcn_mfma_f32_16x16x32_bf16(afr[kk], bfr, acc, 0, 0, 0);
        }
        float bv = brow[c * 16 + gl];
        #pragma unroll
        for (int reg = 0; reg < 4; ++reg) {
            int row = nb + quad * 4 + reg;
            if (row < N)
                out[(size_t)row * 256 + c * 16 + gl] = bf16r(acc[reg] + bv);
        }
    }
}

// edge-parallel edge MLP over dst-sorted csr2 (grid-stride form);
// 16-lane group takes 4 consecutive edges, 16 edges per wave per iteration.
// R3-proven structure: csr2 prefetch ONLY (hv issued fresh each iteration —
// deeper sw pipelining measured -6% via occupancy loss).  uint4-vectorized
// csr2 batch loads; DPP row reduction; coalesced ear edge attrs.
__launch_bounds__(256)
__global__ void edge_mlp_kernel(const uint4* __restrict__ HsHd,
                                const float4* __restrict__ ea,
                                const float4* __restrict__ ear, int use_ear,
                                const uint2* __restrict__ csr2,
                                const float* __restrict__ Wb, const float* __restrict__ Wm2,
                                const float* __restrict__ bm2,
                                float* __restrict__ out, int E) {
    int lane = threadIdx.x & 63;
    int gl = lane & 15, grp = lane >> 4;

    f32x2 wb[4][4], w2[4];
    #pragma unroll
    for (int k = 0; k < 4; ++k) {
        const f32x2* wp = (const f32x2*)(Wb + k * HID + gl * 8);
        #pragma unroll
        for (int p = 0; p < 4; ++p) wb[k][p] = wp[p];
    }
    {
        const f32x2* wp = (const f32x2*)(Wm2 + gl * 8);
        #pragma unroll
        for (int p = 0; p < 4; ++p) w2[p] = wp[p];
    }
    float b2v = bm2[0];

    int gwave = (blockIdx.x * blockDim.x + threadIdx.x) >> 6;
    int nw = (gridDim.x * blockDim.x) >> 6;
    int stride = nw * 16;
    int base = gwave * 16;
    if (base >= E) return;                       // wave-uniform

    uint2 ce[4];
    {
        int i0 = base + grp * 4;
        if (i0 + 3 < E) {
            const uint4* cp = (const uint4*)&csr2[i0];   // 16B-aligned (i0 % 4 == 0)
            uint4 c01 = cp[0], c23 = cp[1];
            ce[0] = make_uint2(c01.x, c01.y); ce[1] = make_uint2(c01.z, c01.w);
            ce[2] = make_uint2(c23.x, c23.y); ce[3] = make_uint2(c23.z, c23.w);
        } else {
            #pragma unroll
            for (int t = 0; t < 4; ++t) {
                int i = i0 + t;
                ce[t] = csr2[(i < E) ? i : 0];
            }
        }
    }

    while (base < E) {
        int nbase = base + stride;

        // issue the long-latency gathers for the current batch
        uint4 hv[4], dv[4];
        float4 eav[4];
        uint eid[4];
        #pragma unroll
        for (int t = 0; t < 4; ++t) {
            uint cx = ce[t].x;
            eid[t] = ce[t].y;
            int i = base + grp * 4 + t;
            int j = (i < E) ? i : 0;
            hv[t] = HsHd[((cx & 0xffffu) << 5) + (uint)gl];
            dv[t] = HsHd[((cx >> 16) << 5) + 16u + (uint)gl];
            eav[t] = use_ear ? ear[j] : ea[eid[t]];
        }

        // prefetch next batch's csr2 (coalesced) while gathers are in flight
        if (nbase < E) {
            int i0 = nbase + grp * 4;
            if (i0 + 3 < E) {
                const uint4* cp = (const uint4*)&csr2[i0];
                uint4 c01 = cp[0], c23 = cp[1];
                ce[0] = make_uint2(c01.x, c01.y); ce[1] = make_uint2(c01.z, c01.w);
                ce[2] = make_uint2(c23.x, c23.y); ce[3] = make_uint2(c23.z, c23.w);
            } else {
                #pragma unroll
                for (int t = 0; t < 4; ++t) {
                    int i = i0 + t;
                    ce[t] = csr2[(i < E) ? i : 0];
                }
            }
        }

        float pr[4];
        #pragma unroll
        for (int t = 0; t < 4; ++t) {
            uint hu[4] = {hv[t].x, hv[t].y, hv[t].z, hv[t].w};
            uint du[4] = {dv[t].x, dv[t].y, dv[t].z, dv[t].w};
            f32x2 e0 = mk2(eav[t].x), e1 = mk2(eav[t].y);
            f32x2 e2 = mk2(eav[t].z), e3 = mk2(eav[t].w);
            f32x2 p2 = mk2(0.f);
            #pragma unroll
            for (int p = 0; p < 4; ++p) {
                f32x2 tt = bf2f(hu[p]) + bf2f(du[p]);
                tt += e0 * wb[0][p];
                tt += e1 * wb[1][p];
                tt += e2 * wb[2][p];
                tt += e3 * wb[3][p];
                tt = max2z(tt);
                p2 += tt * w2[p];
            }
            pr[t] = p2.x + p2.y;
        }
        // 16-lane row reduction via DPP adds (xor1, xor2, ror4, ror8)
        #pragma unroll
        for (int t = 0; t < 4; ++t) {
            float s = pr[t];
            s = dpp_add<0xB1>(s);
            s = dpp_add<0x4E>(s);
            s = dpp_add<0x124>(s);
            s = dpp_add<0x128>(s);
            pr[t] = s;
        }
        if (gl == 0) {
            #pragma unroll
            for (int t = 0; t < 4; ++t) {
                int i = base + grp * 4 + t;
                if (i < E)
                    out[eid[t]] = 1.f / (1.f + exp2f(-1.44269504f * (pr[t] + b2v)));
            }
        }
        base = nbase;
    }
}

// ---------------- launch ----------------

extern "C" void kernel_launch(void* const* d_in, const int* in_sizes, int n_in,
                              void* d_out, int out_size, void* d_ws, size_t ws_size,
                              hipStream_t stream) {
    const float* x    = (const float*)d_in[0];
    const float* ea   = (const float*)d_in[1];
    const float* W1   = (const float*)d_in[2];
    const float* b1   = (const float*)d_in[3];
    const float* W2   = (const float*)d_in[4];
    const float* b2   = (const float*)d_in[5];
    const float* Wm1  = (const float*)d_in[6];
    const float* bm1  = (const float*)d_in[7];
    const float* Wm2  = (const float*)d_in[8];
    const float* bm2  = (const float*)d_in[9];
    const int*   ei   = (const int*)d_in[10];

    const int N = in_sizes[0] / 5;
    const int E = in_sizes[1] / 4;
    const int* src = ei;
    const int* dst = ei + E;
    float* out = (float*)d_out;

    char* ws = (char*)d_ws;
    size_t off = 0;
    auto alloc = [&](size_t bytes) -> void* {
        void* p = ws + off;
        off = (off + bytes + 255) & ~(size_t)255;
        return p;
    };
    int*    cnt    = (int*)alloc((size_t)N * 4);
    int*    excl   = (int*)alloc((size_t)N * 4);
    int*    rowptr = (int*)alloc((size_t)(N + 1) * 4);
    int*    bsum   = (int*)alloc(256 * 4);
    float*  dis    = (float*)alloc((size_t)N * 4);
    int*    rank   = (int*)alloc((size_t)(E + 8) * 4);
    uint2*  csr2   = (uint2*)alloc((size_t)(E + 8) * 8);
    uint4*  xps    = (uint4*)alloc((size_t)N * 16);        // bf16 dis*x, 16 B rows
    uint*   hs1    = (uint*)alloc((size_t)(N + 1) * 64 * 4); // bf16 layer-1 + sentinel row
    uint*   HsHd   = (uint*)alloc((size_t)N * 128 * 4);    // bf16 [N][256]
    uint*   fWc    = (uint*)alloc(16384 * 4);
    float*  brow   = (float*)alloc(256 * 4);
    float*  ear    = (float*)alloc((size_t)(E + 8) * 16);  // dst-sorted edge attrs
    int use_ear = (off <= ws_size) ? 1 : 0;
    (void)n_in; (void)out_size;

    const int NB = (N + 255) / 256;
    const int EB = (E + 255) / 256;

    // zero cnt
    hipMemsetAsync(cnt, 0, (size_t)N * 4, stream);

    // histogram/rank + composite-weight prep (independent, fused for overlap)
    prep_hist<<<EB + 260, 256, 0, stream>>>(dst, cnt, rank, E, EB,
                                            W2, Wm1, b2, bm1, fWc, brow);

    // block-local scan + dis + xps
    scan1x<<<NB, 256, 0, stream>>>(cnt, excl, bsum, dis, x, xps, N);

    // scatter csr2/ear + rowptr finalize (fused, store-only)
    scatter_fin<<<EB + NB, 256, 0, stream>>>(src, dst, excl, bsum, rank,
                                             ea, csr2, ear, rowptr,
                                             use_ear, E, N, NB, EB);

    // layer 1 fused: hs1 = dis * relu((S·x)@W1 + b1), 4 lanes per node
    layer1_kernel<<<(N + 63) / 64, 256, 0, stream>>>(xps, csr2, rowptr, dis, W1, b1, hs1, N);

    // fused: g = S·h1 (group-per-node, 8-deep, barrier-free) ; HsHd = g @ Wc + brow
    agg_gemm<<<(N + 15) / 16, 256, 0, stream>>>((const uint4*)hs1, csr2, rowptr, dis,
                                                (const uint4*)fWc, brow,
                                                (unsigned short*)HsHd, N);

    // per-edge MLP + sigmoid, dst-sorted order, grid-stride (R3-proven form)
    edge_mlp_kernel<<<2048, 256, 0, stream>>>((const uint4*)HsHd,
                                              (const float4*)ea, (const float4*)ear,
                                              use_ear, csr2,
                                              Wm1 + 256 * HID, Wm2, bm2, out, E);
}

// Round 8
// 262.541 us; speedup vs baseline: 1.0136x; 1.0136x over previous
//
#include <hip/hip_runtime.h>
#include <math.h>

#define HID 128
typedef unsigned int uint;
typedef unsigned short u16;
typedef __attribute__((ext_vector_type(8))) __bf16 bf16x8;
typedef __attribute__((ext_vector_type(4))) float f32x4;
typedef __attribute__((ext_vector_type(2))) float f32x2;

// ---------------- bf16 helpers (RNE) ----------------

__device__ __forceinline__ uint pack_bf2(float x, float y) {
    union { float f; uint u; } a, b;
    a.f = x; b.f = y;
    uint lo = (a.u + 0x7fffu + ((a.u >> 16) & 1u)) >> 16;
    uint hi = (b.u + 0x7fffu + ((b.u >> 16) & 1u)) & 0xffff0000u;
    return lo | hi;
}

__device__ __forceinline__ unsigned short bf16r(float x) {
    union { float f; uint u; } a; a.f = x;
    return (unsigned short)((a.u + 0x7fffu + ((a.u >> 16) & 1u)) >> 16);
}

__device__ __forceinline__ f32x2 bf2f(uint v) {
    union { uint u[2]; f32x2 f; } r;
    r.u[0] = v << 16;
    r.u[1] = v & 0xffff0000u;
    return r.f;
}

__device__ __forceinline__ f32x2 mk2(float s) { f32x2 r; r.x = s; r.y = s; return r; }
__device__ __forceinline__ f32x2 max2z(f32x2 a) {
    f32x2 r; r.x = fmaxf(a.x, 0.f); r.y = fmaxf(a.y, 0.f); return r;
}

// DPP-based add of a lane-permuted copy: single VALU op chain, no LDS pipe.
template<int CTRL>
__device__ __forceinline__ float dpp_add(float x) {
    union { float f; int i; } u, r;
    u.f = x;
    r.i = __builtin_amdgcn_update_dpp(0, u.i, CTRL, 0xf, 0xf, true);
    return x + r.f;
}

// ---------------- fused prep + hist_rank ----------------
// blocks < EB: histogram + within-bucket rank (atomic return value)
// blocks >= EB: composite weights Wc = W2 @ [Wm1_top|Wm1_mid] (bf16 MFMA frag
// order) and brow = b2 @ [...] + [bm1|0].
__global__ void prep_hist(const int* __restrict__ dst, int* __restrict__ cnt,
                          int* __restrict__ rank, int E, int EB,
                          const float* __restrict__ W2, const float* __restrict__ Wm1,
                          const float* __restrict__ b2, const float* __restrict__ bm1,
                          uint* __restrict__ fWc, float* __restrict__ brow) {
    if ((int)blockIdx.x < EB) {
        int e = blockIdx.x * blockDim.x + threadIdx.x;
        if (e < E) rank[e] = atomicAdd(&cnt[dst[e]], 1);
        return;
    }
    int t0 = ((int)blockIdx.x - EB) * blockDim.x + threadIdx.x;
    if (t0 < 65536) {       // 16384 outputs * 4 K-slices
        int ks = t0 & 3;
        int i = t0 >> 2;
        int p = i & 3, lane = (i >> 2) & 63, kk = (i >> 8) & 3, ct = i >> 10;
        int k = kk * 32 + (lane >> 4) * 8 + p * 2;
        int n2 = ct * 16 + (lane & 15);
        const float* wmc = (n2 < 128) ? (Wm1 + n2) : (Wm1 + 128 * HID + (n2 - 128));
        const float* w2r0 = W2 + (size_t)k * HID + ks * 32;
        const float* w2r1 = w2r0 + HID;
        const float* wm = wmc + (size_t)(ks * 32) * HID;
        float d0 = 0.f, d1 = 0.f;
        #pragma unroll 8
        for (int j = 0; j < 32; ++j) {
            float w = wm[(size_t)j * HID];
            d0 += w2r0[j] * w;
            d1 += w2r1[j] * w;
        }
        d0 = dpp_add<0xB1>(d0); d0 = dpp_add<0x4E>(d0);
        d1 = dpp_add<0xB1>(d1); d1 = dpp_add<0x4E>(d1);
        if (ks == 0) fWc[i] = pack_bf2(d0, d1);
    } else if (t0 < 65536 + 1024) {
        int r = t0 - 65536;
        int ks = r & 3;
        int i = r >> 2;
        const float* wmc = (i < 128) ? (Wm1 + i) : (Wm1 + 128 * HID + (i - 128));
        float d = 0.f;
        for (int j = ks * 32; j < ks * 32 + 32; ++j) d += b2[j] * wmc[(size_t)j * HID];
        d = dpp_add<0xB1>(d); d = dpp_add<0x4E>(d);
        if (ks == 0) brow[i] = d + ((i < 128) ? bm1[i] : 0.f);
    }
}

// ---------------- scan1x: block-local exclusive scan + dis + xps ----------------
__global__ void scan1x(const int* __restrict__ cnt, int* __restrict__ excl,
                       int* __restrict__ bsum, float* __restrict__ dis,
                       const float* __restrict__ x, uint4* __restrict__ xps, int N) {
    __shared__ int sh[256];
    int tid = threadIdx.x;
    int gid = blockIdx.x * 256 + tid;
    int v = (gid < N) ? cnt[gid] : 0;
    sh[tid] = v;
    __syncthreads();
    for (int o = 1; o < 256; o <<= 1) {
        int t = (tid >= o) ? sh[tid - o] : 0;
        __syncthreads();
        sh[tid] += t;
        __syncthreads();
    }
    if (gid < N) {
        excl[gid] = sh[tid] - v;
        float dn = rsqrtf((float)v + 1.0f);   // deg incl. self-loop
        dis[gid] = dn;
        const float* xr = x + (size_t)gid * 5;
        uint4 pk;
        pk.x = pack_bf2(dn * xr[0], dn * xr[1]);
        pk.y = pack_bf2(dn * xr[2], dn * xr[3]);
        pk.z = pack_bf2(dn * xr[4], 0.f);
        pk.w = 0u;
        xps[gid] = pk;
    }
    if (tid == 255) bsum[blockIdx.x] = sh[255];
}

// ---------------- fused scatter + rowptr finalize (NO atomics) ----------------
// All blocks redundantly scan bsum (<=256 entries) in LDS.
// blocks < EB:  pos = excl[d] + ex[d>>8] + rank[e]; csr2[pos], ear[pos] stores.
// blocks >= EB: rowptr[gid] = excl[gid] + ex[gid>>8]; rowptr[N] = E.
__global__ void scatter_fin(const int* __restrict__ src, const int* __restrict__ dst,
                            const int* __restrict__ excl, const int* __restrict__ bsum,
                            const int* __restrict__ rank,
                            const float4* __restrict__ ea,
                            uint2* __restrict__ csr2, float4* __restrict__ ear,
                            int* __restrict__ rowptr,
                            int use_ear, int E, int N, int NB, int EB) {
    __shared__ int sh[256];
    __shared__ int ex[256];
    int tid = threadIdx.x;
    int v = (tid < NB) ? bsum[tid] : 0;
    sh[tid] = v;
    __syncthreads();
    for (int o = 1; o < 256; o <<= 1) {
        int t = (tid >= o) ? sh[tid - o] : 0;
        __syncthreads();
        sh[tid] += t;
        __syncthreads();
    }
    ex[tid] = sh[tid] - v;
    __syncthreads();

    if ((int)blockIdx.x < EB) {
        int e = blockIdx.x * 256 + tid;
        if (e < E) {
            int d = dst[e];
            int pos = excl[d] + ex[d >> 8] + rank[e];
            csr2[pos] = make_uint2((uint)src[e] | ((uint)d << 16), (uint)e);
            if (use_ear) ear[pos] = ea[e];
        }
    } else {
        int gid = ((int)blockIdx.x - EB) * 256 + tid;
        if (gid < N) rowptr[gid] = excl[gid] + ex[gid >> 8];
        if (gid == N) rowptr[N] = E;
    }
}

// ---------------- fused layer-1: hs1 = dis * relu( (S·x) @ W1 + b1 ) ----------------
// 4 lanes per node (quad): edge gathers split 4-way + DPP quad-reduce.
// xps is 800 KB total -> L2-resident, so the random gathers are cheap.
// Also zero-fills the sentinel row hs1[N] (used by agg_gemm's clamped slots).
__launch_bounds__(256)
__global__ void layer1_kernel(const uint4* __restrict__ xps, const uint2* __restrict__ csr2,
                              const int* __restrict__ rowptr, const float* __restrict__ dis,
                              const float* __restrict__ W1, const float* __restrict__ b1,
                              uint* __restrict__ hs1, int N) {
    __shared__ float sW[5 * HID];
    __shared__ float sb[HID];
    int tid = threadIdx.x;
    for (int i = tid; i < 5 * HID; i += 256) sW[i] = W1[i];
    for (int i = tid; i < HID; i += 256) sb[i] = b1[i];
    if (blockIdx.x == 0 && tid < 16) {
        uint4 z; z.x = 0u; z.y = 0u; z.z = 0u; z.w = 0u;
        ((uint4*)hs1)[(size_t)N * 16 + tid] = z;    // sentinel zero row
    }
    __syncthreads();

    int sub = tid & 3;
    int n = blockIdx.x * 64 + (tid >> 2);
    if (n >= N) return;
    int beg = rowptr[n], end = rowptr[n + 1];
    float a0 = 0.f, a1 = 0.f, a2 = 0.f, a3 = 0.f, a4 = 0.f;
    for (int i = beg + sub; i < end; i += 4) {
        uint s = csr2[i].x & 0xffffu;
        uint4 v = xps[s];
        f32x2 v01 = bf2f(v.x), v23 = bf2f(v.y), v4 = bf2f(v.z);
        a0 += v01.x; a1 += v01.y; a2 += v23.x; a3 += v23.y; a4 += v4.x;
    }
    a0 = dpp_add<0xB1>(a0); a0 = dpp_add<0x4E>(a0);
    a1 = dpp_add<0xB1>(a1); a1 = dpp_add<0x4E>(a1);
    a2 = dpp_add<0xB1>(a2); a2 = dpp_add<0x4E>(a2);
    a3 = dpp_add<0xB1>(a3); a3 = dpp_add<0x4E>(a3);
    a4 = dpp_add<0xB1>(a4); a4 = dpp_add<0x4E>(a4);
    {
        uint4 v = xps[n];   // self-loop term
        f32x2 v01 = bf2f(v.x), v23 = bf2f(v.y), v4 = bf2f(v.z);
        a0 += v01.x; a1 += v01.y; a2 += v23.x; a3 += v23.y; a4 += v4.x;
    }
    float dn = dis[n];
    a0 *= dn; a1 *= dn; a2 *= dn; a3 *= dn; a4 *= dn;   // sx row

    uint* op = hs1 + (size_t)n * 64;
    #pragma unroll
    for (int p = 0; p < 16; ++p) {
        int q = p * 4 + sub;
        int j = q * 2;
        float t0 = sb[j]     + a0 * sW[j]     + a1 * sW[HID + j]     + a2 * sW[2*HID + j]
                             + a3 * sW[3*HID + j] + a4 * sW[4*HID + j];
        float t1 = sb[j + 1] + a0 * sW[j + 1] + a1 * sW[HID + j + 1] + a2 * sW[2*HID + j + 1]
                             + a3 * sW[3*HID + j + 1] + a4 * sW[4*HID + j + 1];
        op[q] = pack_bf2(fmaxf(t0, 0.f) * dn, fmaxf(t1, 0.f) * dn);
    }
}

// ---------------- fused aggregate + GEMM ----------------
// block = 4 waves = 16 nodes.  Phase 1: one 16-lane group per node; each lane owns
// 8 columns (its uint4 slice): no cross-lane ops, no barriers; 8-edge-deep gather
// loop with csr2-index prefetch; out-of-range slots hit the zero sentinel hs1[N].
// Phase 2: wave MFMAs the g tile against 4 of 16 column-tiles of Wc (+brow bias).
__launch_bounds__(256)
__global__ void agg_gemm(const uint4* __restrict__ hs1, const uint2* __restrict__ csr2,
                         const int* __restrict__ rowptr, const float* __restrict__ dis,
                         const uint4* __restrict__ Bf, const float* __restrict__ brow,
                         unsigned short* __restrict__ out, int N) {
    __shared__ uint gt[16][64];
    int tid = threadIdx.x;
    int wave = tid >> 6, lane = tid & 63;
    int gl = lane & 15, grp = lane >> 4;
    int nb = blockIdx.x * 16;
    int r = wave * 4 + grp;          // node slot 0..15 (group-per-node)
    int n = nb + r;
    const uint* cxp = (const uint*)csr2;   // stride-2 view of csr2[i].x

    f32x2 acc0 = mk2(0.f), acc1 = mk2(0.f), acc2 = mk2(0.f), acc3 = mk2(0.f);
    float dn = 0.f;
    if (n < N) {
        dn = dis[n];
        int beg = rowptr[n], end = rowptr[n + 1];
        int i = beg;
        if (i < end) {
            int lst = end - 1;
            uint cb[8];
            #pragma unroll
            for (int t = 0; t < 8; ++t) {
                int a = i + t; a = (a > lst) ? lst : a;
                cb[t] = cxp[(size_t)a * 2];
            }
            while (i < end) {
                uint ss[8];
                #pragma unroll
                for (int t = 0; t < 8; ++t)
                    ss[t] = (i + t < end) ? (cb[t] & 0xffffu) : (uint)N;
                #pragma unroll
                for (int t = 0; t < 8; ++t) {           // prefetch next oct
                    int a = i + 8 + t; a = (a > lst) ? lst : a;
                    cb[t] = cxp[(size_t)a * 2];
                }
                uint4 v0 = hs1[(size_t)ss[0] * 16 + gl];
                uint4 v1 = hs1[(size_t)ss[1] * 16 + gl];
                uint4 v2 = hs1[(size_t)ss[2] * 16 + gl];
                uint4 v3 = hs1[(size_t)ss[3] * 16 + gl];
                uint4 v4 = hs1[(size_t)ss[4] * 16 + gl];
                uint4 v5 = hs1[(size_t)ss[5] * 16 + gl];
                uint4 v6 = hs1[(size_t)ss[6] * 16 + gl];
                uint4 v7 = hs1[(size_t)ss[7] * 16 + gl];
                acc0 += bf2f(v0.x); acc1 += bf2f(v0.y); acc2 += bf2f(v0.z); acc3 += bf2f(v0.w);
                acc0 += bf2f(v1.x); acc1 += bf2f(v1.y); acc2 += bf2f(v1.z); acc3 += bf2f(v1.w);
                acc0 += bf2f(v2.x); acc1 += bf2f(v2.y); acc2 += bf2f(v2.z); acc3 += bf2f(v2.w);
                acc0 += bf2f(v3.x); acc1 += bf2f(v3.y); acc2 += bf2f(v3.z); acc3 += bf2f(v3.w);
                acc0 += bf2f(v4.x); acc1 += bf2f(v4.y); acc2 += bf2f(v4.z); acc3 += bf2f(v4.w);
                acc0 += bf2f(v5.x); acc1 += bf2f(v5.y); acc2 += bf2f(v5.z); acc3 += bf2f(v5.w);
                acc0 += bf2f(v6.x); acc1 += bf2f(v6.y); acc2 += bf2f(v6.z); acc3 += bf2f(v6.w);
                acc0 += bf2f(v7.x); acc1 += bf2f(v7.y); acc2 += bf2f(v7.z); acc3 += bf2f(v7.w);
                i += 8;
            }
        }
        {   // self-loop row
            uint4 sv = hs1[(size_t)n * 16 + gl];
            acc0 += bf2f(sv.x); acc1 += bf2f(sv.y); acc2 += bf2f(sv.z); acc3 += bf2f(sv.w);
        }
    }
    // write g tile row (dn = 0 zeros out-of-range nodes)
    gt[r][gl * 4 + 0] = pack_bf2(acc0.x * dn, acc0.y * dn);
    gt[r][gl * 4 + 1] = pack_bf2(acc1.x * dn, acc1.y * dn);
    gt[r][gl * 4 + 2] = pack_bf2(acc2.x * dn, acc2.y * dn);
    gt[r][gl * 4 + 3] = pack_bf2(acc3.x * dn, acc3.y * dn);
    __syncthreads();

    // phase 2: HsHd = g @ Wc + brow
    int quad = lane >> 4;
    bf16x8 afr[4];
    #pragma unroll
    for (int kk = 0; kk < 4; ++kk)
        afr[kk] = *(const bf16x8*)&gt[gl][kk * 16 + quad * 4];

    for (int cc = 0; cc < 4; ++cc) {
        int c = wave * 4 + cc;
        f32x4 acc = {0.f, 0.f, 0.f, 0.f};
        #pragma unroll
        for (int kk = 0; kk < 4; ++kk) {
            bf16x8 bfr = *(const bf16x8*)&Bf[(size_t)(c * 4 + kk) * 64 + lane];
            acc = __builtin_amdgcn_mfma_f32_16x16x32_bf16(afr[kk], bfr, acc, 0, 0, 0);
        }
        float bv = brow[c * 16 + gl];
        #pragma unroll
        for (int reg = 0; reg < 4; ++reg) {
            int row = nb + quad * 4 + reg;
            if (row < N)
                out[(size_t)row * 256 + c * 16 + gl] = bf16r(acc[reg] + bv);
        }
    }
}

// edge-parallel edge MLP over dst-sorted csr2, processing the range [e0, e1)
// (grid-stride).  16-lane group takes 4 consecutive edges.  R3-proven structure:
// csr2 prefetch only; DPP row reduction; coalesced ear edge attrs.
// Launched as TWO half-range dispatches for rocprof per-kernel visibility.
__launch_bounds__(256)
__global__ void edge_mlp_kernel(const uint4* __restrict__ HsHd,
                                const float4* __restrict__ ea,
                                const float4* __restrict__ ear, int use_ear,
                                const uint2* __restrict__ csr2,
                                const float* __restrict__ Wb, const float* __restrict__ Wm2,
                                const float* __restrict__ bm2,
                                float* __restrict__ out, int e0, int e1, int E) {
    int lane = threadIdx.x & 63;
    int gl = lane & 15, grp = lane >> 4;

    f32x2 wb[4][4], w2[4];
    #pragma unroll
    for (int k = 0; k < 4; ++k) {
        const f32x2* wp = (const f32x2*)(Wb + k * HID + gl * 8);
        #pragma unroll
        for (int p = 0; p < 4; ++p) wb[k][p] = wp[p];
    }
    {
        const f32x2* wp = (const f32x2*)(Wm2 + gl * 8);
        #pragma unroll
        for (int p = 0; p < 4; ++p) w2[p] = wp[p];
    }
    float b2v = bm2[0];

    int gwave = (blockIdx.x * blockDim.x + threadIdx.x) >> 6;
    int nw = (gridDim.x * blockDim.x) >> 6;
    int stride = nw * 16;
    int base = e0 + gwave * 16;
    if (base >= e1) return;                      // wave-uniform

    uint2 ce[4];
    {
        int i0 = base + grp * 4;                 // e0 multiple of 16 -> 16B aligned
        if (i0 + 3 < e1) {
            const uint4* cp = (const uint4*)&csr2[i0];
            uint4 c01 = cp[0], c23 = cp[1];
            ce[0] = make_uint2(c01.x, c01.y); ce[1] = make_uint2(c01.z, c01.w);
            ce[2] = make_uint2(c23.x, c23.y); ce[3] = make_uint2(c23.z, c23.w);
        } else {
            #pragma unroll
            for (int t = 0; t < 4; ++t) {
                int i = i0 + t;
                ce[t] = csr2[(i < e1) ? i : 0];
            }
        }
    }

    while (base < e1) {
        int nbase = base + stride;

        // issue the long-latency gathers for the current batch
        uint4 hv[4], dv[4];
        float4 eav[4];
        uint eid[4];
        #pragma unroll
        for (int t = 0; t < 4; ++t) {
            uint cx = ce[t].x;
            eid[t] = ce[t].y;
            int i = base + grp * 4 + t;
            int j = (i < e1) ? i : 0;
            hv[t] = HsHd[((cx & 0xffffu) << 5) + (uint)gl];
            dv[t] = HsHd[((cx >> 16) << 5) + 16u + (uint)gl];
            eav[t] = use_ear ? ear[j] : ea[eid[t]];
        }

        // prefetch next batch's csr2 (coalesced) while gathers are in flight
        if (nbase < e1) {
            int i0 = nbase + grp * 4;
            if (i0 + 3 < e1) {
                const uint4* cp = (const uint4*)&csr2[i0];
                uint4 c01 = cp[0], c23 = cp[1];
                ce[0] = make_uint2(c01.x, c01.y); ce[1] = make_uint2(c01.z, c01.w);
                ce[2] = make_uint2(c23.x, c23.y); ce[3] = make_uint2(c23.z, c23.w);
            } else {
                #pragma unroll
                for (int t = 0; t < 4; ++t) {
                    int i = i0 + t;
                    ce[t] = csr2[(i < e1) ? i : 0];
                }
            }
        }

        float pr[4];
        #pragma unroll
        for (int t = 0; t < 4; ++t) {
            uint hu[4] = {hv[t].x, hv[t].y, hv[t].z, hv[t].w};
            uint du[4] = {dv[t].x, dv[t].y, dv[t].z, dv[t].w};
            f32x2 e0v = mk2(eav[t].x), e1v = mk2(eav[t].y);
            f32x2 e2v = mk2(eav[t].z), e3v = mk2(eav[t].w);
            f32x2 p2 = mk2(0.f);
            #pragma unroll
            for (int p = 0; p < 4; ++p) {
                f32x2 tt = bf2f(hu[p]) + bf2f(du[p]);
                tt += e0v * wb[0][p];
                tt += e1v * wb[1][p];
                tt += e2v * wb[2][p];
                tt += e3v * wb[3][p];
                tt = max2z(tt);
                p2 += tt * w2[p];
            }
            pr[t] = p2.x + p2.y;
        }
        // 16-lane row reduction via DPP adds (xor1, xor2, ror4, ror8)
        #pragma unroll
        for (int t = 0; t < 4; ++t) {
            float s = pr[t];
            s = dpp_add<0xB1>(s);
            s = dpp_add<0x4E>(s);
            s = dpp_add<0x124>(s);
            s = dpp_add<0x128>(s);
            pr[t] = s;
        }
        if (gl == 0) {
            #pragma unroll
            for (int t = 0; t < 4; ++t) {
                int i = base + grp * 4 + t;
                if (i < e1)
                    out[eid[t]] = 1.f / (1.f + exp2f(-1.44269504f * (pr[t] + b2v)));
            }
        }
        base = nbase;
    }
}

// ---------------- launch ----------------

extern "C" void kernel_launch(void* const* d_in, const int* in_sizes, int n_in,
                              void* d_out, int out_size, void* d_ws, size_t ws_size,
                              hipStream_t stream) {
    const float* x    = (const float*)d_in[0];
    const float* ea   = (const float*)d_in[1];
    const float* W1   = (const float*)d_in[2];
    const float* b1   = (const float*)d_in[3];
    const float* W2   = (const float*)d_in[4];
    const float* b2   = (const float*)d_in[5];
    const float* Wm1  = (const float*)d_in[6];
    const float* bm1  = (const float*)d_in[7];
    const float* Wm2  = (const float*)d_in[8];
    const float* bm2  = (const float*)d_in[9];
    const int*   ei   = (const int*)d_in[10];

    const int N = in_sizes[0] / 5;
    const int E = in_sizes[1] / 4;
    const int* src = ei;
    const int* dst = ei + E;
    float* out = (float*)d_out;

    char* ws = (char*)d_ws;
    size_t off = 0;
    auto alloc = [&](size_t bytes) -> void* {
        void* p = ws + off;
        off = (off + bytes + 255) & ~(size_t)255;
        return p;
    };
    int*    cnt    = (int*)alloc((size_t)N * 4);
    int*    excl   = (int*)alloc((size_t)N * 4);
    int*    rowptr = (int*)alloc((size_t)(N + 1) * 4);
    int*    bsum   = (int*)alloc(256 * 4);
    float*  dis    = (float*)alloc((size_t)N * 4);
    int*    rank   = (int*)alloc((size_t)(E + 8) * 4);
    uint2*  csr2   = (uint2*)alloc((size_t)(E + 8) * 8);
    uint4*  xps    = (uint4*)alloc((size_t)N * 16);        // bf16 dis*x, 16 B rows
    uint*   hs1    = (uint*)alloc((size_t)(N + 1) * 64 * 4); // bf16 layer-1 + sentinel row
    uint*   HsHd   = (uint*)alloc((size_t)N * 128 * 4);    // bf16 [N][256]
    uint*   fWc    = (uint*)alloc(16384 * 4);
    float*  brow   = (float*)alloc(256 * 4);
    float4* ear    = (float4*)alloc((size_t)(E + 8) * 16); // dst-sorted edge attrs
    int use_ear = (off <= ws_size) ? 1 : 0;
    (void)n_in; (void)out_size;

    const int NB = (N + 255) / 256;
    const int EB = (E + 255) / 256;

    // zero cnt
    hipMemsetAsync(cnt, 0, (size_t)N * 4, stream);

    // histogram/rank + composite-weight prep (independent, fused for overlap)
    prep_hist<<<EB + 260, 256, 0, stream>>>(dst, cnt, rank, E, EB,
                                            W2, Wm1, b2, bm1, fWc, brow);

    // block-local scan + dis + xps
    scan1x<<<NB, 256, 0, stream>>>(cnt, excl, bsum, dis, x, xps, N);

    // scatter csr2/ear + rowptr finalize (fused, store-only)
    scatter_fin<<<EB + NB, 256, 0, stream>>>(src, dst, excl, bsum, rank,
                                             (const float4*)ea,
                                             csr2, ear, rowptr,
                                             use_ear, E, N, NB, EB);

    // layer 1 fused: hs1 = dis * relu((S·x)@W1 + b1), 4 lanes per node
    layer1_kernel<<<(N + 63) / 64, 256, 0, stream>>>(xps, csr2, rowptr, dis, W1, b1, hs1, N);

    // fused: g = S·h1 (group-per-node, 8-deep, barrier-free) ; HsHd = g @ Wc + brow
    agg_gemm<<<(N + 15) / 16, 256, 0, stream>>>((const uint4*)hs1, csr2, rowptr, dis,
                                                (const uint4*)fWc, brow,
                                                (unsigned short*)HsHd, N);

    // per-edge MLP + sigmoid, dst-sorted, two half-range dispatches
    // (visibility: lets rocprof top-5 surface the mid-tier kernels)
    int Eh = ((E / 2) + 15) & ~15;               // split point, multiple of 16
    edge_mlp_kernel<<<2048, 256, 0, stream>>>((const uint4*)HsHd,
                                              (const float4*)ea, (const float4*)ear,
                                              use_ear, csr2,
                                              Wm1 + 256 * HID, Wm2, bm2, out, 0, Eh, E);
    edge_mlp_kernel<<<2048, 256, 0, stream>>>((const uint4*)HsHd,
                                              (const float4*)ea, (const float4*)ear,
                                              use_ear, csr2,
                                              Wm1 + 256 * HID, Wm2, bm2, out, Eh, E, E);
}

// Round 9
// 257.217 us; speedup vs baseline: 1.0346x; 1.0207x over previous
//
#include <hip/hip_runtime.h>
#include <math.h>

#define HID 128
typedef unsigned int uint;
typedef unsigned short u16;
typedef __attribute__((ext_vector_type(8))) __bf16 bf16x8;
typedef __attribute__((ext_vector_type(4))) float f32x4;
typedef __attribute__((ext_vector_type(2))) float f32x2;

// ---------------- bf16 helpers (RNE) ----------------

__device__ __forceinline__ uint pack_bf2(float x, float y) {
    union { float f; uint u; } a, b;
    a.f = x; b.f = y;
    uint lo = (a.u + 0x7fffu + ((a.u >> 16) & 1u)) >> 16;
    uint hi = (b.u + 0x7fffu + ((b.u >> 16) & 1u)) & 0xffff0000u;
    return lo | hi;
}

__device__ __forceinline__ unsigned short bf16r(float x) {
    union { float f; uint u; } a; a.f = x;
    return (unsigned short)((a.u + 0x7fffu + ((a.u >> 16) & 1u)) >> 16);
}

__device__ __forceinline__ f32x2 bf2f(uint v) {
    union { uint u[2]; f32x2 f; } r;
    r.u[0] = v << 16;
    r.u[1] = v & 0xffff0000u;
    return r.f;
}

__device__ __forceinline__ f32x2 mk2(float s) { f32x2 r; r.x = s; r.y = s; return r; }
__device__ __forceinline__ f32x2 max2z(f32x2 a) {
    f32x2 r; r.x = fmaxf(a.x, 0.f); r.y = fmaxf(a.y, 0.f); return r;
}

// DPP-based add of a lane-permuted copy: single VALU op chain, no LDS pipe.
template<int CTRL>
__device__ __forceinline__ float dpp_add(float x) {
    union { float f; int i; } u, r;
    u.f = x;
    r.i = __builtin_amdgcn_update_dpp(0, u.i, CTRL, 0xf, 0xf, true);
    return x + r.f;
}

// ---------------- fused prep + hist_rank ----------------
// blocks < EB8: histogram + within-bucket rank, 8 EDGES PER THREAD.
//   Device-scope atomics execute as serial RMW transactions at the coherence
//   point (memory-side L3; per-XCD L2 non-coherent) — measured 0.7% VALU, 28 MB
//   writes, pure latency-bound at 1 atomic/thread.  8 independent atomics per
//   thread raises outstanding RMWs per wave 64 -> 512.
// blocks >= EB8: composite weights Wc = W2 @ [Wm1_top|Wm1_mid] (bf16 MFMA frag
// order) and brow = b2 @ [...] + [bm1|0].
__global__ void prep_hist(const int* __restrict__ dst, int* __restrict__ cnt,
                          int* __restrict__ rank, int E, int EB8,
                          const float* __restrict__ W2, const float* __restrict__ Wm1,
                          const float* __restrict__ b2, const float* __restrict__ bm1,
                          uint* __restrict__ fWc, float* __restrict__ brow) {
    if ((int)blockIdx.x < EB8) {
        int base = (blockIdx.x * 256 + threadIdx.x) * 8;
        if (base >= E) return;
        if (base + 7 < E) {
            int4 d0 = *(const int4*)(dst + base);
            int4 d1 = *(const int4*)(dst + base + 4);
            int r0 = atomicAdd(&cnt[d0.x], 1);
            int r1 = atomicAdd(&cnt[d0.y], 1);
            int r2 = atomicAdd(&cnt[d0.z], 1);
            int r3 = atomicAdd(&cnt[d0.w], 1);
            int r4 = atomicAdd(&cnt[d1.x], 1);
            int r5 = atomicAdd(&cnt[d1.y], 1);
            int r6 = atomicAdd(&cnt[d1.z], 1);
            int r7 = atomicAdd(&cnt[d1.w], 1);
            int4 w0; w0.x = r0; w0.y = r1; w0.z = r2; w0.w = r3;
            int4 w1; w1.x = r4; w1.y = r5; w1.z = r6; w1.w = r7;
            *(int4*)(rank + base) = w0;
            *(int4*)(rank + base + 4) = w1;
        } else {
            for (int e = base; e < E; ++e) rank[e] = atomicAdd(&cnt[dst[e]], 1);
        }
        return;
    }
    int t0 = ((int)blockIdx.x - EB8) * blockDim.x + threadIdx.x;
    if (t0 < 65536) {       // 16384 outputs * 4 K-slices
        int ks = t0 & 3;
        int i = t0 >> 2;
        int p = i & 3, lane = (i >> 2) & 63, kk = (i >> 8) & 3, ct = i >> 10;
        int k = kk * 32 + (lane >> 4) * 8 + p * 2;
        int n2 = ct * 16 + (lane & 15);
        const float* wmc = (n2 < 128) ? (Wm1 + n2) : (Wm1 + 128 * HID + (n2 - 128));
        const float* w2r0 = W2 + (size_t)k * HID + ks * 32;
        const float* w2r1 = w2r0 + HID;
        const float* wm = wmc + (size_t)(ks * 32) * HID;
        float d0 = 0.f, d1 = 0.f;
        #pragma unroll 8
        for (int j = 0; j < 32; ++j) {
            float w = wm[(size_t)j * HID];
            d0 += w2r0[j] * w;
            d1 += w2r1[j] * w;
        }
        d0 = dpp_add<0xB1>(d0); d0 = dpp_add<0x4E>(d0);
        d1 = dpp_add<0xB1>(d1); d1 = dpp_add<0x4E>(d1);
        if (ks == 0) fWc[i] = pack_bf2(d0, d1);
    } else if (t0 < 65536 + 1024) {
        int r = t0 - 65536;
        int ks = r & 3;
        int i = r >> 2;
        const float* wmc = (i < 128) ? (Wm1 + i) : (Wm1 + 128 * HID + (i - 128));
        float d = 0.f;
        for (int j = ks * 32; j < ks * 32 + 32; ++j) d += b2[j] * wmc[(size_t)j * HID];
        d = dpp_add<0xB1>(d); d = dpp_add<0x4E>(d);
        if (ks == 0) brow[i] = d + ((i < 128) ? bm1[i] : 0.f);
    }
}

// ---------------- scan1x: block-local exclusive scan + dis + xps ----------------
__global__ void scan1x(const int* __restrict__ cnt, int* __restrict__ excl,
                       int* __restrict__ bsum, float* __restrict__ dis,
                       const float* __restrict__ x, uint4* __restrict__ xps, int N) {
    __shared__ int sh[256];
    int tid = threadIdx.x;
    int gid = blockIdx.x * 256 + tid;
    int v = (gid < N) ? cnt[gid] : 0;
    sh[tid] = v;
    __syncthreads();
    for (int o = 1; o < 256; o <<= 1) {
        int t = (tid >= o) ? sh[tid - o] : 0;
        __syncthreads();
        sh[tid] += t;
        __syncthreads();
    }
    if (gid < N) {
        excl[gid] = sh[tid] - v;
        float dn = rsqrtf((float)v + 1.0f);   // deg incl. self-loop
        dis[gid] = dn;
        const float* xr = x + (size_t)gid * 5;
        uint4 pk;
        pk.x = pack_bf2(dn * xr[0], dn * xr[1]);
        pk.y = pack_bf2(dn * xr[2], dn * xr[3]);
        pk.z = pack_bf2(dn * xr[4], 0.f);
        pk.w = 0u;
        xps[gid] = pk;
    }
    if (tid == 255) bsum[blockIdx.x] = sh[255];
}

// ---------------- fused scatter + rowptr finalize (NO atomics) ----------------
// All blocks redundantly scan bsum (<=256 entries) in LDS.
// blocks < EB:  pos = excl[d] + ex[d>>8] + rank[e]; csr2[pos], ear[pos] stores.
// blocks >= EB: rowptr[gid] = excl[gid] + ex[gid>>8]; rowptr[N] = E.
__global__ void scatter_fin(const int* __restrict__ src, const int* __restrict__ dst,
                            const int* __restrict__ excl, const int* __restrict__ bsum,
                            const int* __restrict__ rank,
                            const float4* __restrict__ ea,
                            uint2* __restrict__ csr2, float4* __restrict__ ear,
                            int* __restrict__ rowptr,
                            int use_ear, int E, int N, int NB, int EB) {
    __shared__ int sh[256];
    __shared__ int ex[256];
    int tid = threadIdx.x;
    int v = (tid < NB) ? bsum[tid] : 0;
    sh[tid] = v;
    __syncthreads();
    for (int o = 1; o < 256; o <<= 1) {
        int t = (tid >= o) ? sh[tid - o] : 0;
        __syncthreads();
        sh[tid] += t;
        __syncthreads();
    }
    ex[tid] = sh[tid] - v;
    __syncthreads();

    if ((int)blockIdx.x < EB) {
        int e = blockIdx.x * 256 + tid;
        if (e < E) {
            int d = dst[e];
            int pos = excl[d] + ex[d >> 8] + rank[e];
            csr2[pos] = make_uint2((uint)src[e] | ((uint)d << 16), (uint)e);
            if (use_ear) ear[pos] = ea[e];
        }
    } else {
        int gid = ((int)blockIdx.x - EB) * 256 + tid;
        if (gid < N) rowptr[gid] = excl[gid] + ex[gid >> 8];
        if (gid == N) rowptr[N] = E;
    }
}

// ---------------- fused layer-1: hs1 = dis * relu( (S·x) @ W1 + b1 ) ----------------
// 4 lanes per node (quad): edge gathers split 4-way + DPP quad-reduce.
// xps is 800 KB total -> L2-resident, so the random gathers are cheap.
// Also zero-fills the sentinel row hs1[N] (used by agg_gemm's clamped slots).
__launch_bounds__(256)
__global__ void layer1_kernel(const uint4* __restrict__ xps, const uint2* __restrict__ csr2,
                              const int* __restrict__ rowptr, const float* __restrict__ dis,
                              const float* __restrict__ W1, const float* __restrict__ b1,
                              uint* __restrict__ hs1, int N) {
    __shared__ float sW[5 * HID];
    __shared__ float sb[HID];
    int tid = threadIdx.x;
    for (int i = tid; i < 5 * HID; i += 256) sW[i] = W1[i];
    for (int i = tid; i < HID; i += 256) sb[i] = b1[i];
    if (blockIdx.x == 0 && tid < 16) {
        uint4 z; z.x = 0u; z.y = 0u; z.z = 0u; z.w = 0u;
        ((uint4*)hs1)[(size_t)N * 16 + tid] = z;    // sentinel zero row
    }
    __syncthreads();

    int sub = tid & 3;
    int n = blockIdx.x * 64 + (tid >> 2);
    if (n >= N) return;
    int beg = rowptr[n], end = rowptr[n + 1];
    float a0 = 0.f, a1 = 0.f, a2 = 0.f, a3 = 0.f, a4 = 0.f;
    for (int i = beg + sub; i < end; i += 4) {
        uint s = csr2[i].x & 0xffffu;
        uint4 v = xps[s];
        f32x2 v01 = bf2f(v.x), v23 = bf2f(v.y), v4 = bf2f(v.z);
        a0 += v01.x; a1 += v01.y; a2 += v23.x; a3 += v23.y; a4 += v4.x;
    }
    a0 = dpp_add<0xB1>(a0); a0 = dpp_add<0x4E>(a0);
    a1 = dpp_add<0xB1>(a1); a1 = dpp_add<0x4E>(a1);
    a2 = dpp_add<0xB1>(a2); a2 = dpp_add<0x4E>(a2);
    a3 = dpp_add<0xB1>(a3); a3 = dpp_add<0x4E>(a3);
    a4 = dpp_add<0xB1>(a4); a4 = dpp_add<0x4E>(a4);
    {
        uint4 v = xps[n];   // self-loop term
        f32x2 v01 = bf2f(v.x), v23 = bf2f(v.y), v4 = bf2f(v.z);
        a0 += v01.x; a1 += v01.y; a2 += v23.x; a3 += v23.y; a4 += v4.x;
    }
    float dn = dis[n];
    a0 *= dn; a1 *= dn; a2 *= dn; a3 *= dn; a4 *= dn;   // sx row

    uint* op = hs1 + (size_t)n * 64;
    #pragma unroll
    for (int p = 0; p < 16; ++p) {
        int q = p * 4 + sub;
        int j = q * 2;
        float t0 = sb[j]     + a0 * sW[j]     + a1 * sW[HID + j]     + a2 * sW[2*HID + j]
                             + a3 * sW[3*HID + j] + a4 * sW[4*HID + j];
        float t1 = sb[j + 1] + a0 * sW[j + 1] + a1 * sW[HID + j + 1] + a2 * sW[2*HID + j + 1]
                             + a3 * sW[3*HID + j + 1] + a4 * sW[4*HID + j + 1];
        op[q] = pack_bf2(fmaxf(t0, 0.f) * dn, fmaxf(t1, 0.f) * dn);
    }
}

// ---------------- fused aggregate + GEMM ----------------
// block = 4 waves = 16 nodes.  Phase 1: one 16-lane group per node; each lane owns
// 8 columns (its uint4 slice): no cross-lane ops, no barriers; 8-edge-deep gather
// loop with csr2-index prefetch; out-of-range slots hit the zero sentinel hs1[N].
// Phase 2: wave MFMAs the g tile against 4 of 16 column-tiles of Wc (+brow bias).
__launch_bounds__(256)
__global__ void agg_gemm(const uint4* __restrict__ hs1, const uint2* __restrict__ csr2,
                         const int* __restrict__ rowptr, const float* __restrict__ dis,
                         const uint4* __restrict__ Bf, const float* __restrict__ brow,
                         unsigned short* __restrict__ out, int N) {
    __shared__ uint gt[16][64];
    int tid = threadIdx.x;
    int wave = tid >> 6, lane = tid & 63;
    int gl = lane & 15, grp = lane >> 4;
    int nb = blockIdx.x * 16;
    int r = wave * 4 + grp;          // node slot 0..15 (group-per-node)
    int n = nb + r;
    const uint* cxp = (const uint*)csr2;   // stride-2 view of csr2[i].x

    f32x2 acc0 = mk2(0.f), acc1 = mk2(0.f), acc2 = mk2(0.f), acc3 = mk2(0.f);
    float dn = 0.f;
    if (n < N) {
        dn = dis[n];
        int beg = rowptr[n], end = rowptr[n + 1];
        int i = beg;
        if (i < end) {
            int lst = end - 1;
            uint cb[8];
            #pragma unroll
            for (int t = 0; t < 8; ++t) {
                int a = i + t; a = (a > lst) ? lst : a;
                cb[t] = cxp[(size_t)a * 2];
            }
            while (i < end) {
                uint ss[8];
                #pragma unroll
                for (int t = 0; t < 8; ++t)
                    ss[t] = (i + t < end) ? (cb[t] & 0xffffu) : (uint)N;
                #pragma unroll
                for (int t = 0; t < 8; ++t) {           // prefetch next oct
                    int a = i + 8 + t; a = (a > lst) ? lst : a;
                    cb[t] = cxp[(size_t)a * 2];
                }
                uint4 v0 = hs1[(size_t)ss[0] * 16 + gl];
                uint4 v1 = hs1[(size_t)ss[1] * 16 + gl];
                uint4 v2 = hs1[(size_t)ss[2] * 16 + gl];
                uint4 v3 = hs1[(size_t)ss[3] * 16 + gl];
                uint4 v4 = hs1[(size_t)ss[4] * 16 + gl];
                uint4 v5 = hs1[(size_t)ss[5] * 16 + gl];
                uint4 v6 = hs1[(size_t)ss[6] * 16 + gl];
                uint4 v7 = hs1[(size_t)ss[7] * 16 + gl];
                acc0 += bf2f(v0.x); acc1 += bf2f(v0.y); acc2 += bf2f(v0.z); acc3 += bf2f(v0.w);
                acc0 += bf2f(v1.x); acc1 += bf2f(v1.y); acc2 += bf2f(v1.z); acc3 += bf2f(v1.w);
                acc0 += bf2f(v2.x); acc1 += bf2f(v2.y); acc2 += bf2f(v2.z); acc3 += bf2f(v2.w);
                acc0 += bf2f(v3.x); acc1 += bf2f(v3.y); acc2 += bf2f(v3.z); acc3 += bf2f(v3.w);
                acc0 += bf2f(v4.x); acc1 += bf2f(v4.y); acc2 += bf2f(v4.z); acc3 += bf2f(v4.w);
                acc0 += bf2f(v5.x); acc1 += bf2f(v5.y); acc2 += bf2f(v5.z); acc3 += bf2f(v5.w);
                acc0 += bf2f(v6.x); acc1 += bf2f(v6.y); acc2 += bf2f(v6.z); acc3 += bf2f(v6.w);
                acc0 += bf2f(v7.x); acc1 += bf2f(v7.y); acc2 += bf2f(v7.z); acc3 += bf2f(v7.w);
                i += 8;
            }
        }
        {   // self-loop row
            uint4 sv = hs1[(size_t)n * 16 + gl];
            acc0 += bf2f(sv.x); acc1 += bf2f(sv.y); acc2 += bf2f(sv.z); acc3 += bf2f(sv.w);
        }
    }
    // write g tile row (dn = 0 zeros out-of-range nodes)
    gt[r][gl * 4 + 0] = pack_bf2(acc0.x * dn, acc0.y * dn);
    gt[r][gl * 4 + 1] = pack_bf2(acc1.x * dn, acc1.y * dn);
    gt[r][gl * 4 + 2] = pack_bf2(acc2.x * dn, acc2.y * dn);
    gt[r][gl * 4 + 3] = pack_bf2(acc3.x * dn, acc3.y * dn);
    __syncthreads();

    // phase 2: HsHd = g @ Wc + brow
    int quad = lane >> 4;
    bf16x8 afr[4];
    #pragma unroll
    for (int kk = 0; kk < 4; ++kk)
        afr[kk] = *(const bf16x8*)&gt[gl][kk * 16 + quad * 4];

    for (int cc = 0; cc < 4; ++cc) {
        int c = wave * 4 + cc;
        f32x4 acc = {0.f, 0.f, 0.f, 0.f};
        #pragma unroll
        for (int kk = 0; kk < 4; ++kk) {
            bf16x8 bfr = *(const bf16x8*)&Bf[(size_t)(c * 4 + kk) * 64 + lane];
            acc = __builtin_amdgcn_mfma_f32_16x16x32_bf16(afr[kk], bfr, acc, 0, 0, 0);
        }
        float bv = brow[c * 16 + gl];
        #pragma unroll
        for (int reg = 0; reg < 4; ++reg) {
            int row = nb + quad * 4 + reg;
            if (row < N)
                out[(size_t)row * 256 + c * 16 + gl] = bf16r(acc[reg] + bv);
        }
    }
}

// edge-parallel edge MLP over dst-sorted csr2, processing the range [e0, e1)
// (grid-stride).  16-lane group takes 4 consecutive edges.  R3-proven structure:
// csr2 prefetch only; DPP row reduction; coalesced ear edge attrs.
// Launched as TWO half-range dispatches for rocprof per-kernel visibility.
__launch_bounds__(256)
__global__ void edge_mlp_kernel(const uint4* __restrict__ HsHd,
                                const float4* __restrict__ ea,
                                const float4* __restrict__ ear, int use_ear,
                                const uint2* __restrict__ csr2,
                                const float* __restrict__ Wb, const float* __restrict__ Wm2,
                                const float* __restrict__ bm2,
                                float* __restrict__ out, int e0, int e1, int E) {
    int lane = threadIdx.x & 63;
    int gl = lane & 15, grp = lane >> 4;

    f32x2 wb[4][4], w2[4];
    #pragma unroll
    for (int k = 0; k < 4; ++k) {
        const f32x2* wp = (const f32x2*)(Wb + k * HID + gl * 8);
        #pragma unroll
        for (int p = 0; p < 4; ++p) wb[k][p] = wp[p];
    }
    {
        const f32x2* wp = (const f32x2*)(Wm2 + gl * 8);
        #pragma unroll
        for (int p = 0; p < 4; ++p) w2[p] = wp[p];
    }
    float b2v = bm2[0];

    int gwave = (blockIdx.x * blockDim.x + threadIdx.x) >> 6;
    int nw = (gridDim.x * blockDim.x) >> 6;
    int stride = nw * 16;
    int base = e0 + gwave * 16;
    if (base >= e1) return;                      // wave-uniform

    uint2 ce[4];
    {
        int i0 = base + grp * 4;                 // e0 multiple of 16 -> 16B aligned
        if (i0 + 3 < e1) {
            const uint4* cp = (const uint4*)&csr2[i0];
            uint4 c01 = cp[0], c23 = cp[1];
            ce[0] = make_uint2(c01.x, c01.y); ce[1] = make_uint2(c01.z, c01.w);
            ce[2] = make_uint2(c23.x, c23.y); ce[3] = make_uint2(c23.z, c23.w);
        } else {
            #pragma unroll
            for (int t = 0; t < 4; ++t) {
                int i = i0 + t;
                ce[t] = csr2[(i < e1) ? i : 0];
            }
        }
    }

    while (base < e1) {
        int nbase = base + stride;

        // issue the long-latency gathers for the current batch
        uint4 hv[4], dv[4];
        float4 eav[4];
        uint eid[4];
        #pragma unroll
        for (int t = 0; t < 4; ++t) {
            uint cx = ce[t].x;
            eid[t] = ce[t].y;
            int i = base + grp * 4 + t;
            int j = (i < e1) ? i : 0;
            hv[t] = HsHd[((cx & 0xffffu) << 5) + (uint)gl];
            dv[t] = HsHd[((cx >> 16) << 5) + 16u + (uint)gl];
            eav[t] = use_ear ? ear[j] : ea[eid[t]];
        }

        // prefetch next batch's csr2 (coalesced) while gathers are in flight
        if (nbase < e1) {
            int i0 = nbase + grp * 4;
            if (i0 + 3 < e1) {
                const uint4* cp = (const uint4*)&csr2[i0];
                uint4 c01 = cp[0], c23 = cp[1];
                ce[0] = make_uint2(c01.x, c01.y); ce[1] = make_uint2(c01.z, c01.w);
                ce[2] = make_uint2(c23.x, c23.y); ce[3] = make_uint2(c23.z, c23.w);
            } else {
                #pragma unroll
                for (int t = 0; t < 4; ++t) {
                    int i = i0 + t;
                    ce[t] = csr2[(i < e1) ? i : 0];
                }
            }
        }

        float pr[4];
        #pragma unroll
        for (int t = 0; t < 4; ++t) {
            uint hu[4] = {hv[t].x, hv[t].y, hv[t].z, hv[t].w};
            uint du[4] = {dv[t].x, dv[t].y, dv[t].z, dv[t].w};
            f32x2 e0v = mk2(eav[t].x), e1v = mk2(eav[t].y);
            f32x2 e2v = mk2(eav[t].z), e3v = mk2(eav[t].w);
            f32x2 p2 = mk2(0.f);
            #pragma unroll
            for (int p = 0; p < 4; ++p) {
                f32x2 tt = bf2f(hu[p]) + bf2f(du[p]);
                tt += e0v * wb[0][p];
                tt += e1v * wb[1][p];
                tt += e2v * wb[2][p];
                tt += e3v * wb[3][p];
                tt = max2z(tt);
                p2 += tt * w2[p];
            }
            pr[t] = p2.x + p2.y;
        }
        // 16-lane row reduction via DPP adds (xor1, xor2, ror4, ror8)
        #pragma unroll
        for (int t = 0; t < 4; ++t) {
            float s = pr[t];
            s = dpp_add<0xB1>(s);
            s = dpp_add<0x4E>(s);
            s = dpp_add<0x124>(s);
            s = dpp_add<0x128>(s);
            pr[t] = s;
        }
        if (gl == 0) {
            #pragma unroll
            for (int t = 0; t < 4; ++t) {
                int i = base + grp * 4 + t;
                if (i < e1)
                    out[eid[t]] = 1.f / (1.f + exp2f(-1.44269504f * (pr[t] + b2v)));
            }
        }
        base = nbase;
    }
}

// ---------------- launch ----------------

extern "C" void kernel_launch(void* const* d_in, const int* in_sizes, int n_in,
                              void* d_out, int out_size, void* d_ws, size_t ws_size,
                              hipStream_t stream) {
    const float* x    = (const float*)d_in[0];
    const float* ea   = (const float*)d_in[1];
    const float* W1   = (const float*)d_in[2];
    const float* b1   = (const float*)d_in[3];
    const float* W2   = (const float*)d_in[4];
    const float* b2   = (const float*)d_in[5];
    const float* Wm1  = (const float*)d_in[6];
    const float* bm1  = (const float*)d_in[7];
    const float* Wm2  = (const float*)d_in[8];
    const float* bm2  = (const float*)d_in[9];
    const int*   ei   = (const int*)d_in[10];

    const int N = in_sizes[0] / 5;
    const int E = in_sizes[1] / 4;
    const int* src = ei;
    const int* dst = ei + E;
    float* out = (float*)d_out;

    char* ws = (char*)d_ws;
    size_t off = 0;
    auto alloc = [&](size_t bytes) -> void* {
        void* p = ws + off;
        off = (off + bytes + 255) & ~(size_t)255;
        return p;
    };
    int*    cnt    = (int*)alloc((size_t)N * 4);
    int*    excl   = (int*)alloc((size_t)N * 4);
    int*    rowptr = (int*)alloc((size_t)(N + 1) * 4);
    int*    bsum   = (int*)alloc(256 * 4);
    float*  dis    = (float*)alloc((size_t)N * 4);
    int*    rank   = (int*)alloc((size_t)(E + 8) * 4);
    uint2*  csr2   = (uint2*)alloc((size_t)(E + 8) * 8);
    uint4*  xps    = (uint4*)alloc((size_t)N * 16);        // bf16 dis*x, 16 B rows
    uint*   hs1    = (uint*)alloc((size_t)(N + 1) * 64 * 4); // bf16 layer-1 + sentinel row
    uint*   HsHd   = (uint*)alloc((size_t)N * 128 * 4);    // bf16 [N][256]
    uint*   fWc    = (uint*)alloc(16384 * 4);
    float*  brow   = (float*)alloc(256 * 4);
    float4* ear    = (float4*)alloc((size_t)(E + 8) * 16); // dst-sorted edge attrs
    int use_ear = (off <= ws_size) ? 1 : 0;
    (void)n_in; (void)out_size;

    const int NB = (N + 255) / 256;
    const int EB = (E + 255) / 256;
    const int EB8 = (E + 2047) / 2048;           // 8 edges per thread

    // zero cnt
    hipMemsetAsync(cnt, 0, (size_t)N * 4, stream);

    // histogram/rank (8 edges/thread, 512 outstanding atomics/wave)
    // + composite-weight prep (independent, fused for overlap)
    prep_hist<<<EB8 + 260, 256, 0, stream>>>(dst, cnt, rank, E, EB8,
                                             W2, Wm1, b2, bm1, fWc, brow);

    // block-local scan + dis + xps
    scan1x<<<NB, 256, 0, stream>>>(cnt, excl, bsum, dis, x, xps, N);

    // scatter csr2/ear + rowptr finalize (fused, store-only)
    scatter_fin<<<EB + NB, 256, 0, stream>>>(src, dst, excl, bsum, rank,
                                             (const float4*)ea,
                                             csr2, ear, rowptr,
                                             use_ear, E, N, NB, EB);

    // layer 1 fused: hs1 = dis * relu((S·x)@W1 + b1), 4 lanes per node
    layer1_kernel<<<(N + 63) / 64, 256, 0, stream>>>(xps, csr2, rowptr, dis, W1, b1, hs1, N);

    // fused: g = S·h1 (group-per-node, 8-deep, barrier-free) ; HsHd = g @ Wc + brow
    agg_gemm<<<(N + 15) / 16, 256, 0, stream>>>((const uint4*)hs1, csr2, rowptr, dis,
                                                (const uint4*)fWc, brow,
                                                (unsigned short*)HsHd, N);

    // per-edge MLP + sigmoid, dst-sorted, two half-range dispatches
    // (visibility: lets rocprof top-5 surface the mid-tier kernels)
    int Eh = ((E / 2) + 15) & ~15;               // split point, multiple of 16
    edge_mlp_kernel<<<2048, 256, 0, stream>>>((const uint4*)HsHd,
                                              (const float4*)ea, (const float4*)ear,
                                              use_ear, csr2,
                                              Wm1 + 256 * HID, Wm2, bm2, out, 0, Eh, E);
    edge_mlp_kernel<<<2048, 256, 0, stream>>>((const uint4*)HsHd,
                                              (const float4*)ea, (const float4*)ear,
                                              use_ear, csr2,
                                              Wm1 + 256 * HID, Wm2, bm2, out, Eh, E, E);
}

// Round 10
// 249.567 us; speedup vs baseline: 1.0663x; 1.0306x over previous
//
#include <hip/hip_runtime.h>
#include <math.h>

#define HID 128
typedef unsigned int uint;
typedef unsigned short u16;
typedef __attribute__((ext_vector_type(8))) __bf16 bf16x8;
typedef __attribute__((ext_vector_type(4))) float f32x4;
typedef __attribute__((ext_vector_type(2))) float f32x2;

// ---------------- bf16 helpers (RNE) ----------------

__device__ __forceinline__ uint pack_bf2(float x, float y) {
    union { float f; uint u; } a, b;
    a.f = x; b.f = y;
    uint lo = (a.u + 0x7fffu + ((a.u >> 16) & 1u)) >> 16;
    uint hi = (b.u + 0x7fffu + ((b.u >> 16) & 1u)) & 0xffff0000u;
    return lo | hi;
}

__device__ __forceinline__ unsigned short bf16r(float x) {
    union { float f; uint u; } a; a.f = x;
    return (unsigned short)((a.u + 0x7fffu + ((a.u >> 16) & 1u)) >> 16);
}

__device__ __forceinline__ f32x2 bf2f(uint v) {
    union { uint u[2]; f32x2 f; } r;
    r.u[0] = v << 16;
    r.u[1] = v & 0xffff0000u;
    return r.f;
}

__device__ __forceinline__ f32x2 mk2(float s) { f32x2 r; r.x = s; r.y = s; return r; }
__device__ __forceinline__ f32x2 max2z(f32x2 a) {
    f32x2 r; r.x = fmaxf(a.x, 0.f); r.y = fmaxf(a.y, 0.f); return r;
}

// DPP-based add of a lane-permuted copy: single VALU op chain, no LDS pipe.
template<int CTRL>
__device__ __forceinline__ float dpp_add(float x) {
    union { float f; int i; } u, r;
    u.f = x;
    r.i = __builtin_amdgcn_update_dpp(0, u.i, CTRL, 0xf, 0xf, true);
    return x + r.f;
}

// ---------------- fused prep + hist_rank ----------------
// blocks < EB8: histogram + within-bucket rank, 8 EDGES PER THREAD
//   (512 outstanding RMWs/wave — proved R9: removed prep_hist from top-5).
// blocks >= EB8: composite weights Wc = W2 @ [Wm1_top|Wm1_mid] (bf16 MFMA frag
// order) and brow = b2 @ [...] + [bm1|0].
__global__ void prep_hist(const int* __restrict__ dst, int* __restrict__ cnt,
                          int* __restrict__ rank, int E, int EB8,
                          const float* __restrict__ W2, const float* __restrict__ Wm1,
                          const float* __restrict__ b2, const float* __restrict__ bm1,
                          uint* __restrict__ fWc, float* __restrict__ brow) {
    if ((int)blockIdx.x < EB8) {
        int base = (blockIdx.x * 256 + threadIdx.x) * 8;
        if (base >= E) return;
        if (base + 7 < E) {
            int4 d0 = *(const int4*)(dst + base);
            int4 d1 = *(const int4*)(dst + base + 4);
            int r0 = atomicAdd(&cnt[d0.x], 1);
            int r1 = atomicAdd(&cnt[d0.y], 1);
            int r2 = atomicAdd(&cnt[d0.z], 1);
            int r3 = atomicAdd(&cnt[d0.w], 1);
            int r4 = atomicAdd(&cnt[d1.x], 1);
            int r5 = atomicAdd(&cnt[d1.y], 1);
            int r6 = atomicAdd(&cnt[d1.z], 1);
            int r7 = atomicAdd(&cnt[d1.w], 1);
            int4 w0; w0.x = r0; w0.y = r1; w0.z = r2; w0.w = r3;
            int4 w1; w1.x = r4; w1.y = r5; w1.z = r6; w1.w = r7;
            *(int4*)(rank + base) = w0;
            *(int4*)(rank + base + 4) = w1;
        } else {
            for (int e = base; e < E; ++e) rank[e] = atomicAdd(&cnt[dst[e]], 1);
        }
        return;
    }
    int t0 = ((int)blockIdx.x - EB8) * blockDim.x + threadIdx.x;
    if (t0 < 65536) {       // 16384 outputs * 4 K-slices
        int ks = t0 & 3;
        int i = t0 >> 2;
        int p = i & 3, lane = (i >> 2) & 63, kk = (i >> 8) & 3, ct = i >> 10;
        int k = kk * 32 + (lane >> 4) * 8 + p * 2;
        int n2 = ct * 16 + (lane & 15);
        const float* wmc = (n2 < 128) ? (Wm1 + n2) : (Wm1 + 128 * HID + (n2 - 128));
        const float* w2r0 = W2 + (size_t)k * HID + ks * 32;
        const float* w2r1 = w2r0 + HID;
        const float* wm = wmc + (size_t)(ks * 32) * HID;
        float d0 = 0.f, d1 = 0.f;
        #pragma unroll 8
        for (int j = 0; j < 32; ++j) {
            float w = wm[(size_t)j * HID];
            d0 += w2r0[j] * w;
            d1 += w2r1[j] * w;
        }
        d0 = dpp_add<0xB1>(d0); d0 = dpp_add<0x4E>(d0);
        d1 = dpp_add<0xB1>(d1); d1 = dpp_add<0x4E>(d1);
        if (ks == 0) fWc[i] = pack_bf2(d0, d1);
    } else if (t0 < 65536 + 1024) {
        int r = t0 - 65536;
        int ks = r & 3;
        int i = r >> 2;
        const float* wmc = (i < 128) ? (Wm1 + i) : (Wm1 + 128 * HID + (i - 128));
        float d = 0.f;
        for (int j = ks * 32; j < ks * 32 + 32; ++j) d += b2[j] * wmc[(size_t)j * HID];
        d = dpp_add<0xB1>(d); d = dpp_add<0x4E>(d);
        if (ks == 0) brow[i] = d + ((i < 128) ? bm1[i] : 0.f);
    }
}

// ---------------- scan1x: block-local exclusive scan + dis + xps ----------------
__global__ void scan1x(const int* __restrict__ cnt, int* __restrict__ excl,
                       int* __restrict__ bsum, float* __restrict__ dis,
                       const float* __restrict__ x, uint4* __restrict__ xps, int N) {
    __shared__ int sh[256];
    int tid = threadIdx.x;
    int gid = blockIdx.x * 256 + tid;
    int v = (gid < N) ? cnt[gid] : 0;
    sh[tid] = v;
    __syncthreads();
    for (int o = 1; o < 256; o <<= 1) {
        int t = (tid >= o) ? sh[tid - o] : 0;
        __syncthreads();
        sh[tid] += t;
        __syncthreads();
    }
    if (gid < N) {
        excl[gid] = sh[tid] - v;
        float dn = rsqrtf((float)v + 1.0f);   // deg incl. self-loop
        dis[gid] = dn;
        const float* xr = x + (size_t)gid * 5;
        uint4 pk;
        pk.x = pack_bf2(dn * xr[0], dn * xr[1]);
        pk.y = pack_bf2(dn * xr[2], dn * xr[3]);
        pk.z = pack_bf2(dn * xr[4], 0.f);
        pk.w = 0u;
        xps[gid] = pk;
    }
    if (tid == 255) bsum[blockIdx.x] = sh[255];
}

// ---------------- fused scatter + rowptr finalize (NO atomics) ----------------
// All blocks redundantly scan bsum (<=256 entries) in LDS.
// blocks < EB:  pos = excl[d] + ex[d>>8] + rank[e]; csr2[pos], ear[pos] stores.
// blocks >= EB: rowptr[gid] = excl[gid] + ex[gid>>8]; rowptr[N] = E.
__global__ void scatter_fin(const int* __restrict__ src, const int* __restrict__ dst,
                            const int* __restrict__ excl, const int* __restrict__ bsum,
                            const int* __restrict__ rank,
                            const float4* __restrict__ ea,
                            uint2* __restrict__ csr2, float4* __restrict__ ear,
                            int* __restrict__ rowptr,
                            int use_ear, int E, int N, int NB, int EB) {
    __shared__ int sh[256];
    __shared__ int ex[256];
    int tid = threadIdx.x;
    int v = (tid < NB) ? bsum[tid] : 0;
    sh[tid] = v;
    __syncthreads();
    for (int o = 1; o < 256; o <<= 1) {
        int t = (tid >= o) ? sh[tid - o] : 0;
        __syncthreads();
        sh[tid] += t;
        __syncthreads();
    }
    ex[tid] = sh[tid] - v;
    __syncthreads();

    if ((int)blockIdx.x < EB) {
        int e = blockIdx.x * 256 + tid;
        if (e < E) {
            int d = dst[e];
            int pos = excl[d] + ex[d >> 8] + rank[e];
            csr2[pos] = make_uint2((uint)src[e] | ((uint)d << 16), (uint)e);
            if (use_ear) ear[pos] = ea[e];
        }
    } else {
        int gid = ((int)blockIdx.x - EB) * 256 + tid;
        if (gid < N) rowptr[gid] = excl[gid] + ex[gid >> 8];
        if (gid == N) rowptr[N] = E;
    }
}

// ---------------- fused layer-1: hs1 = dis * relu( (S·x) @ W1 + b1 ) ----------------
// 4 lanes per node (quad): edge gathers split 4-way + DPP quad-reduce.
// xps is 800 KB total -> L2-resident, so the random gathers are cheap.
// Also zero-fills the sentinel row hs1[N] (used by agg_gemm's clamped slots).
__launch_bounds__(256)
__global__ void layer1_kernel(const uint4* __restrict__ xps, const uint2* __restrict__ csr2,
                              const int* __restrict__ rowptr, const float* __restrict__ dis,
                              const float* __restrict__ W1, const float* __restrict__ b1,
                              uint* __restrict__ hs1, int N) {
    __shared__ float sW[5 * HID];
    __shared__ float sb[HID];
    int tid = threadIdx.x;
    for (int i = tid; i < 5 * HID; i += 256) sW[i] = W1[i];
    for (int i = tid; i < HID; i += 256) sb[i] = b1[i];
    if (blockIdx.x == 0 && tid < 16) {
        uint4 z; z.x = 0u; z.y = 0u; z.z = 0u; z.w = 0u;
        ((uint4*)hs1)[(size_t)N * 16 + tid] = z;    // sentinel zero row
    }
    __syncthreads();

    int sub = tid & 3;
    int n = blockIdx.x * 64 + (tid >> 2);
    if (n >= N) return;
    int beg = rowptr[n], end = rowptr[n + 1];
    float a0 = 0.f, a1 = 0.f, a2 = 0.f, a3 = 0.f, a4 = 0.f;
    for (int i = beg + sub; i < end; i += 4) {
        uint s = csr2[i].x & 0xffffu;
        uint4 v = xps[s];
        f32x2 v01 = bf2f(v.x), v23 = bf2f(v.y), v4 = bf2f(v.z);
        a0 += v01.x; a1 += v01.y; a2 += v23.x; a3 += v23.y; a4 += v4.x;
    }
    a0 = dpp_add<0xB1>(a0); a0 = dpp_add<0x4E>(a0);
    a1 = dpp_add<0xB1>(a1); a1 = dpp_add<0x4E>(a1);
    a2 = dpp_add<0xB1>(a2); a2 = dpp_add<0x4E>(a2);
    a3 = dpp_add<0xB1>(a3); a3 = dpp_add<0x4E>(a3);
    a4 = dpp_add<0xB1>(a4); a4 = dpp_add<0x4E>(a4);
    {
        uint4 v = xps[n];   // self-loop term
        f32x2 v01 = bf2f(v.x), v23 = bf2f(v.y), v4 = bf2f(v.z);
        a0 += v01.x; a1 += v01.y; a2 += v23.x; a3 += v23.y; a4 += v4.x;
    }
    float dn = dis[n];
    a0 *= dn; a1 *= dn; a2 *= dn; a3 *= dn; a4 *= dn;   // sx row

    uint* op = hs1 + (size_t)n * 64;
    #pragma unroll
    for (int p = 0; p < 16; ++p) {
        int q = p * 4 + sub;
        int j = q * 2;
        float t0 = sb[j]     + a0 * sW[j]     + a1 * sW[HID + j]     + a2 * sW[2*HID + j]
                             + a3 * sW[3*HID + j] + a4 * sW[4*HID + j];
        float t1 = sb[j + 1] + a0 * sW[j + 1] + a1 * sW[HID + j + 1] + a2 * sW[2*HID + j + 1]
                             + a3 * sW[3*HID + j + 1] + a4 * sW[4*HID + j + 1];
        op[q] = pack_bf2(fmaxf(t0, 0.f) * dn, fmaxf(t1, 0.f) * dn);
    }
}

// ---------------- fused aggregate + GEMM ----------------
// block = 4 waves = 16 nodes.  Phase 1: one 16-lane group per node; each lane owns
// 8 columns: no cross-lane ops, no barriers; 8-edge-deep gather loop with csr2
// prefetch; out-of-range slots hit the zero sentinel hs1[N].
// Phase 2: wave MFMAs the g tile against 4 of 16 column-tiles of Wc (+brow bias).
// gt row stride = 68 words (not 64): 64 = 2x32 banks made the phase-2
// ds_read_b128 a 16-way conflict (measured 1.4M conflict-cycles); 68 rotates
// each row by 4 banks -> 2-way (free).
__launch_bounds__(256)
__global__ void agg_gemm(const uint4* __restrict__ hs1, const uint2* __restrict__ csr2,
                         const int* __restrict__ rowptr, const float* __restrict__ dis,
                         const uint4* __restrict__ Bf, const float* __restrict__ brow,
                         unsigned short* __restrict__ out, int N) {
    __shared__ uint gt[16][68];
    int tid = threadIdx.x;
    int wave = tid >> 6, lane = tid & 63;
    int gl = lane & 15, grp = lane >> 4;
    int nb = blockIdx.x * 16;
    int r = wave * 4 + grp;          // node slot 0..15 (group-per-node)
    int n = nb + r;
    const uint* cxp = (const uint*)csr2;   // stride-2 view of csr2[i].x

    f32x2 acc0 = mk2(0.f), acc1 = mk2(0.f), acc2 = mk2(0.f), acc3 = mk2(0.f);
    float dn = 0.f;
    if (n < N) {
        dn = dis[n];
        int beg = rowptr[n], end = rowptr[n + 1];
        int i = beg;
        if (i < end) {
            int lst = end - 1;
            uint cb[8];
            #pragma unroll
            for (int t = 0; t < 8; ++t) {
                int a = i + t; a = (a > lst) ? lst : a;
                cb[t] = cxp[(size_t)a * 2];
            }
            while (i < end) {
                uint ss[8];
                #pragma unroll
                for (int t = 0; t < 8; ++t)
                    ss[t] = (i + t < end) ? (cb[t] & 0xffffu) : (uint)N;
                #pragma unroll
                for (int t = 0; t < 8; ++t) {           // prefetch next oct
                    int a = i + 8 + t; a = (a > lst) ? lst : a;
                    cb[t] = cxp[(size_t)a * 2];
                }
                uint4 v0 = hs1[(size_t)ss[0] * 16 + gl];
                uint4 v1 = hs1[(size_t)ss[1] * 16 + gl];
                uint4 v2 = hs1[(size_t)ss[2] * 16 + gl];
                uint4 v3 = hs1[(size_t)ss[3] * 16 + gl];
                uint4 v4 = hs1[(size_t)ss[4] * 16 + gl];
                uint4 v5 = hs1[(size_t)ss[5] * 16 + gl];
                uint4 v6 = hs1[(size_t)ss[6] * 16 + gl];
                uint4 v7 = hs1[(size_t)ss[7] * 16 + gl];
                acc0 += bf2f(v0.x); acc1 += bf2f(v0.y); acc2 += bf2f(v0.z); acc3 += bf2f(v0.w);
                acc0 += bf2f(v1.x); acc1 += bf2f(v1.y); acc2 += bf2f(v1.z); acc3 += bf2f(v1.w);
                acc0 += bf2f(v2.x); acc1 += bf2f(v2.y); acc2 += bf2f(v2.z); acc3 += bf2f(v2.w);
                acc0 += bf2f(v3.x); acc1 += bf2f(v3.y); acc2 += bf2f(v3.z); acc3 += bf2f(v3.w);
                acc0 += bf2f(v4.x); acc1 += bf2f(v4.y); acc2 += bf2f(v4.z); acc3 += bf2f(v4.w);
                acc0 += bf2f(v5.x); acc1 += bf2f(v5.y); acc2 += bf2f(v5.z); acc3 += bf2f(v5.w);
                acc0 += bf2f(v6.x); acc1 += bf2f(v6.y); acc2 += bf2f(v6.z); acc3 += bf2f(v6.w);
                acc0 += bf2f(v7.x); acc1 += bf2f(v7.y); acc2 += bf2f(v7.z); acc3 += bf2f(v7.w);
                i += 8;
            }
        }
        {   // self-loop row
            uint4 sv = hs1[(size_t)n * 16 + gl];
            acc0 += bf2f(sv.x); acc1 += bf2f(sv.y); acc2 += bf2f(sv.z); acc3 += bf2f(sv.w);
        }
    }
    // write g tile row (dn = 0 zeros out-of-range nodes)
    gt[r][gl * 4 + 0] = pack_bf2(acc0.x * dn, acc0.y * dn);
    gt[r][gl * 4 + 1] = pack_bf2(acc1.x * dn, acc1.y * dn);
    gt[r][gl * 4 + 2] = pack_bf2(acc2.x * dn, acc2.y * dn);
    gt[r][gl * 4 + 3] = pack_bf2(acc3.x * dn, acc3.y * dn);
    __syncthreads();

    // phase 2: HsHd = g @ Wc + brow
    int quad = lane >> 4;
    bf16x8 afr[4];
    #pragma unroll
    for (int kk = 0; kk < 4; ++kk)
        afr[kk] = *(const bf16x8*)&gt[gl][kk * 16 + quad * 4];

    for (int cc = 0; cc < 4; ++cc) {
        int c = wave * 4 + cc;
        f32x4 acc = {0.f, 0.f, 0.f, 0.f};
        #pragma unroll
        for (int kk = 0; kk < 4; ++kk) {
            bf16x8 bfr = *(const bf16x8*)&Bf[(size_t)(c * 4 + kk) * 64 + lane];
            acc = __builtin_amdgcn_mfma_f32_16x16x32_bf16(afr[kk], bfr, acc, 0, 0, 0);
        }
        float bv = brow[c * 16 + gl];
        #pragma unroll
        for (int reg = 0; reg < 4; ++reg) {
            int row = nb + quad * 4 + reg;
            if (row < N)
                out[(size_t)row * 256 + c * 16 + gl] = bf16r(acc[reg] + bv);
        }
    }
}

// edge-parallel edge MLP over dst-sorted csr2 (grid-stride form);
// 16-lane group takes 4 consecutive edges, 16 edges per wave per iteration.
// R3-proven structure: csr2 prefetch only; DPP row reduction; coalesced ear.
__launch_bounds__(256)
__global__ void edge_mlp_kernel(const uint4* __restrict__ HsHd,
                                const float4* __restrict__ ea,
                                const float4* __restrict__ ear, int use_ear,
                                const uint2* __restrict__ csr2,
                                const float* __restrict__ Wb, const float* __restrict__ Wm2,
                                const float* __restrict__ bm2,
                                float* __restrict__ out, int E) {
    int lane = threadIdx.x & 63;
    int gl = lane & 15, grp = lane >> 4;

    f32x2 wb[4][4], w2[4];
    #pragma unroll
    for (int k = 0; k < 4; ++k) {
        const f32x2* wp = (const f32x2*)(Wb + k * HID + gl * 8);
        #pragma unroll
        for (int p = 0; p < 4; ++p) wb[k][p] = wp[p];
    }
    {
        const f32x2* wp = (const f32x2*)(Wm2 + gl * 8);
        #pragma unroll
        for (int p = 0; p < 4; ++p) w2[p] = wp[p];
    }
    float b2v = bm2[0];

    int gwave = (blockIdx.x * blockDim.x + threadIdx.x) >> 6;
    int nw = (gridDim.x * blockDim.x) >> 6;
    int stride = nw * 16;
    int base = gwave * 16;
    if (base >= E) return;                       // wave-uniform

    uint2 ce[4];
    {
        int i0 = base + grp * 4;
        if (i0 + 3 < E) {
            const uint4* cp = (const uint4*)&csr2[i0];   // 16B-aligned (i0 % 4 == 0)
            uint4 c01 = cp[0], c23 = cp[1];
            ce[0] = make_uint2(c01.x, c01.y); ce[1] = make_uint2(c01.z, c01.w);
            ce[2] = make_uint2(c23.x, c23.y); ce[3] = make_uint2(c23.z, c23.w);
        } else {
            #pragma unroll
            for (int t = 0; t < 4; ++t) {
                int i = i0 + t;
                ce[t] = csr2[(i < E) ? i : 0];
            }
        }
    }

    while (base < E) {
        int nbase = base + stride;

        // issue the long-latency gathers for the current batch
        uint4 hv[4], dv[4];
        float4 eav[4];
        uint eid[4];
        #pragma unroll
        for (int t = 0; t < 4; ++t) {
            uint cx = ce[t].x;
            eid[t] = ce[t].y;
            int i = base + grp * 4 + t;
            int j = (i < E) ? i : 0;
            hv[t] = HsHd[((cx & 0xffffu) << 5) + (uint)gl];
            dv[t] = HsHd[((cx >> 16) << 5) + 16u + (uint)gl];
            eav[t] = use_ear ? ear[j] : ea[eid[t]];
        }

        // prefetch next batch's csr2 (coalesced) while gathers are in flight
        if (nbase < E) {
            int i0 = nbase + grp * 4;
            if (i0 + 3 < E) {
                const uint4* cp = (const uint4*)&csr2[i0];
                uint4 c01 = cp[0], c23 = cp[1];
                ce[0] = make_uint2(c01.x, c01.y); ce[1] = make_uint2(c01.z, c01.w);
                ce[2] = make_uint2(c23.x, c23.y); ce[3] = make_uint2(c23.z, c23.w);
            } else {
                #pragma unroll
                for (int t = 0; t < 4; ++t) {
                    int i = i0 + t;
                    ce[t] = csr2[(i < E) ? i : 0];
                }
            }
        }

        float pr[4];
        #pragma unroll
        for (int t = 0; t < 4; ++t) {
            uint hu[4] = {hv[t].x, hv[t].y, hv[t].z, hv[t].w};
            uint du[4] = {dv[t].x, dv[t].y, dv[t].z, dv[t].w};
            f32x2 e0 = mk2(eav[t].x), e1 = mk2(eav[t].y);
            f32x2 e2 = mk2(eav[t].z), e3 = mk2(eav[t].w);
            f32x2 p2 = mk2(0.f);
            #pragma unroll
            for (int p = 0; p < 4; ++p) {
                f32x2 tt = bf2f(hu[p]) + bf2f(du[p]);
                tt += e0 * wb[0][p];
                tt += e1 * wb[1][p];
                tt += e2 * wb[2][p];
                tt += e3 * wb[3][p];
                tt = max2z(tt);
                p2 += tt * w2[p];
            }
            pr[t] = p2.x + p2.y;
        }
        // 16-lane row reduction via DPP adds (xor1, xor2, ror4, ror8)
        #pragma unroll
        for (int t = 0; t < 4; ++t) {
            float s = pr[t];
            s = dpp_add<0xB1>(s);
            s = dpp_add<0x4E>(s);
            s = dpp_add<0x124>(s);
            s = dpp_add<0x128>(s);
            pr[t] = s;
        }
        if (gl == 0) {
            #pragma unroll
            for (int t = 0; t < 4; ++t) {
                int i = base + grp * 4 + t;
                if (i < E)
                    out[eid[t]] = 1.f / (1.f + exp2f(-1.44269504f * (pr[t] + b2v)));
            }
        }
        base = nbase;
    }
}

// ---------------- launch ----------------

extern "C" void kernel_launch(void* const* d_in, const int* in_sizes, int n_in,
                              void* d_out, int out_size, void* d_ws, size_t ws_size,
                              hipStream_t stream) {
    const float* x    = (const float*)d_in[0];
    const float* ea   = (const float*)d_in[1];
    const float* W1   = (const float*)d_in[2];
    const float* b1   = (const float*)d_in[3];
    const float* W2   = (const float*)d_in[4];
    const float* b2   = (const float*)d_in[5];
    const float* Wm1  = (const float*)d_in[6];
    const float* bm1  = (const float*)d_in[7];
    const float* Wm2  = (const float*)d_in[8];
    const float* bm2  = (const float*)d_in[9];
    const int*   ei   = (const int*)d_in[10];

    const int N = in_sizes[0] / 5;
    const int E = in_sizes[1] / 4;
    const int* src = ei;
    const int* dst = ei + E;
    float* out = (float*)d_out;

    char* ws = (char*)d_ws;
    size_t off = 0;
    auto alloc = [&](size_t bytes) -> void* {
        void* p = ws + off;
        off = (off + bytes + 255) & ~(size_t)255;
        return p;
    };
    int*    cnt    = (int*)alloc((size_t)N * 4);
    int*    excl   = (int*)alloc((size_t)N * 4);
    int*    rowptr = (int*)alloc((size_t)(N + 1) * 4);
    int*    bsum   = (int*)alloc(256 * 4);
    float*  dis    = (float*)alloc((size_t)N * 4);
    int*    rank   = (int*)alloc((size_t)(E + 8) * 4);
    uint2*  csr2   = (uint2*)alloc((size_t)(E + 8) * 8);
    uint4*  xps    = (uint4*)alloc((size_t)N * 16);        // bf16 dis*x, 16 B rows
    uint*   hs1    = (uint*)alloc((size_t)(N + 1) * 64 * 4); // bf16 layer-1 + sentinel row
    uint*   HsHd   = (uint*)alloc((size_t)N * 128 * 4);    // bf16 [N][256]
    uint*   fWc    = (uint*)alloc(16384 * 4);
    float*  brow   = (float*)alloc(256 * 4);
    float4* ear    = (float4*)alloc((size_t)(E + 8) * 16); // dst-sorted edge attrs
    int use_ear = (off <= ws_size) ? 1 : 0;
    (void)n_in; (void)out_size;

    const int NB = (N + 255) / 256;
    const int EB = (E + 255) / 256;
    const int EB8 = (E + 2047) / 2048;           // 8 edges per thread

    // zero cnt
    hipMemsetAsync(cnt, 0, (size_t)N * 4, stream);

    // histogram/rank (8 edges/thread) + composite-weight prep (fused for overlap)
    prep_hist<<<EB8 + 260, 256, 0, stream>>>(dst, cnt, rank, E, EB8,
                                             W2, Wm1, b2, bm1, fWc, brow);

    // block-local scan + dis + xps
    scan1x<<<NB, 256, 0, stream>>>(cnt, excl, bsum, dis, x, xps, N);

    // scatter csr2/ear + rowptr finalize (fused, store-only)
    scatter_fin<<<EB + NB, 256, 0, stream>>>(src, dst, excl, bsum, rank,
                                             (const float4*)ea,
                                             csr2, ear, rowptr,
                                             use_ear, E, N, NB, EB);

    // layer 1 fused: hs1 = dis * relu((S·x)@W1 + b1), 4 lanes per node
    layer1_kernel<<<(N + 63) / 64, 256, 0, stream>>>(xps, csr2, rowptr, dis, W1, b1, hs1, N);

    // fused: g = S·h1 (group-per-node, 8-deep, barrier-free) ; HsHd = g @ Wc + brow
    agg_gemm<<<(N + 15) / 16, 256, 0, stream>>>((const uint4*)hs1, csr2, rowptr, dis,
                                                (const uint4*)fWc, brow,
                                                (unsigned short*)HsHd, N);

    // per-edge MLP + sigmoid, dst-sorted order, grid-stride (single dispatch)
    edge_mlp_kernel<<<2048, 256, 0, stream>>>((const uint4*)HsHd,
                                              (const float4*)ea, (const float4*)ear,
                                              use_ear, csr2,
                                              Wm1 + 256 * HID, Wm2, bm2, out, E);
}